// Round 1
// baseline (808.881 us; speedup 1.0000x reference)
//
#include <hip/hip_runtime.h>

typedef unsigned short u16;
typedef __attribute__((ext_vector_type(8))) short bf16x8;
typedef __attribute__((ext_vector_type(4))) float f32x4;
typedef __attribute__((ext_vector_type(4))) unsigned short u16x4;

__device__ __forceinline__ u16 f2b(float f) {
  union { float f; unsigned u; } x; x.f = f;
  unsigned u = x.u;
  return (u16)((u + 0x7fffu + ((u >> 16) & 1u)) >> 16);
}
__device__ __forceinline__ float b2f(u16 b) {
  union { unsigned u; float f; } x; x.u = ((unsigned)b) << 16;
  return x.f;
}

struct GemmOffsets { long a[4]; long b[4]; long c[4]; };

// ---------------- tiny prep kernels ----------------
__global__ void zero_flags_k(int* flags) {
  if (threadIdx.x < 16) flags[threadIdx.x] = 0;
}

// per-head all-zero detection for rel_bias (correct for ANY input)
__global__ void bias_scan_k(const float* __restrict__ rel, int* __restrict__ flags) {
  long base = (long)blockIdx.x * 65536;
  int h = blockIdx.x >> 6;  // 64 blocks per head (head = 2048*2048 floats)
  const float4* p = (const float4*)(rel + base);
  bool nz = false;
  for (int i = threadIdx.x; i < 16384; i += 256) {
    float4 v = p[i];
    nz = nz || (v.x != 0.f) || (v.y != 0.f) || (v.z != 0.f) || (v.w != 0.f);
  }
  if (nz) atomicOr(flags + h, 1);
}

__global__ void cvt_f2b_k(const float* __restrict__ in, u16* __restrict__ out) {
  long i = ((long)blockIdx.x * 256 + threadIdx.x) * 4;
  float4 v = *(const float4*)(in + i);
  u16x4 o;
  o[0] = f2b(v.x); o[1] = f2b(v.y); o[2] = f2b(v.z); o[3] = f2b(v.w);
  *(u16x4*)(out + i) = o;
}

// out[c][r] = in[r][c]; f32 -> bf16. grid (C/64, R/64), 256 thr
__global__ void transpose_f2b_k(const float* __restrict__ in, u16* __restrict__ out,
                                int R, int C) {
  __shared__ float tile[64][68];
  int r0 = blockIdx.y * 64, c0 = blockIdx.x * 64;
  int t = threadIdx.x;
  for (int ch = t; ch < 1024; ch += 256) {
    int r = ch >> 4, q = ch & 15;
    float4 v = *(const float4*)(in + (long)(r0 + r) * C + c0 + q * 4);
    tile[r][q * 4 + 0] = v.x; tile[r][q * 4 + 1] = v.y;
    tile[r][q * 4 + 2] = v.z; tile[r][q * 4 + 3] = v.w;
  }
  __syncthreads();
  for (int ch = t; ch < 1024; ch += 256) {
    int cc = ch >> 4, g = ch & 15;
    u16x4 o;
    o[0] = f2b(tile[g * 4 + 0][cc]); o[1] = f2b(tile[g * 4 + 1][cc]);
    o[2] = f2b(tile[g * 4 + 2][cc]); o[3] = f2b(tile[g * 4 + 3][cc]);
    *(u16x4*)(out + (long)(c0 + cc) * R + r0 + g * 4) = o;
  }
}

// out[z][c][r] = in[z][r][c]; bf16. grid (C/64, R/64, Z), 256 thr
__global__ void transpose_b2b_k(const u16* __restrict__ in, u16* __restrict__ out,
                                int R, int C) {
  __shared__ u16 tile[64][80];
  long zb = (long)blockIdx.z * R * C;
  int r0 = blockIdx.y * 64, c0 = blockIdx.x * 64;
  int t = threadIdx.x;
  for (int ch = t; ch < 512; ch += 256) {
    int r = ch >> 3, q = ch & 7;
    *(bf16x8*)&tile[r][q * 8] =
        *(const bf16x8*)(in + zb + (long)(r0 + r) * C + c0 + q * 8);
  }
  __syncthreads();
  for (int ch = t; ch < 512; ch += 256) {
    int cc = ch >> 3, q = ch & 7;
    bf16x8 v;
#pragma unroll
    for (int k = 0; k < 8; ++k) v[k] = (short)tile[q * 8 + k][cc];
    *(bf16x8*)(out + zb + (long)(c0 + cc) * R + r0 + q * 8) = v;
  }
}

// h = irfft(exp(-j*alpha), n=2048): direct cosine sum with exact integer phase
__global__ void conv_h_k(const float* __restrict__ alpha, float* __restrict__ hbuf) {
  int tt = blockIdx.x * 256 + threadIdx.x;  // 0..2047
  float a = alpha[0];
  const float wph = 3.14159265358979323846f / 1024.f;
  float acc = 1.0f;  // j = 0 term
  for (int j = 1; j < 1024; ++j) {
    int ph = (j * tt) & 2047;
    acc += 2.f * expf(-a * (float)j) * cosf((float)ph * wph);
  }
  {
    int ph = (1024 * tt) & 2047;
    acc += expf(-a * 1024.f) * cosf((float)ph * wph);
  }
  hbuf[tt] = acc * (1.f / 2048.f);
}

__global__ void hb_fill_k(const float* __restrict__ hbuf, u16* __restrict__ Hb) {
  long idx = (long)blockIdx.x * 256 + threadIdx.x;  // < 2048*2048
  int tt = (int)(idx >> 11), u = (int)(idx & 2047);
  Hb[idx] = f2b(hbuf[(tt - u) & 2047]);
}

// ---------------- shared bf16 MFMA GEMM: C = A[M,K] @ Bt[N,K]^T ----------------
// 128x128 tile, BK=64, 4 waves, XOR-swizzled LDS (16B chunk ^ (row&7)).
// BIAS_MODE: 0 none, 1 bias[col], 2 bias[(row>>11)*ldc+col]
template<int BIAS_MODE, bool OUT_F32>
__global__ __launch_bounds__(256)
void gemm_bt_k(const u16* __restrict__ A, int lda,
               const u16* __restrict__ Bt, int ldb,
               void* __restrict__ Cv, int ldc, int K,
               const float* __restrict__ bias, GemmOffsets offs) {
  __shared__ u16 As[128 * 64];
  __shared__ u16 Bs[128 * 64];
  const int z = blockIdx.z;
  const u16* Ab = A + offs.a[z];
  const u16* Bb = Bt + offs.b[z];
  const int m0 = blockIdx.y * 128, n0 = blockIdx.x * 128;
  const int t = threadIdx.x;
  const int w = t >> 6, l = t & 63;
  const int wr = (w >> 1) * 64, wc = (w & 1) * 64;
  const int lrow = l & 15, lk = l >> 4;

  f32x4 acc[4][4] = {};

  for (int k0 = 0; k0 < K; k0 += 64) {
    __syncthreads();
    for (int ch = t; ch < 1024; ch += 256) {
      int row = ch >> 3, cg = ch & 7;
      int slot = row * 64 + ((cg ^ (row & 7)) << 3);
      *(bf16x8*)&As[slot] = *(const bf16x8*)(Ab + (long)(m0 + row) * lda + k0 + cg * 8);
      *(bf16x8*)&Bs[slot] = *(const bf16x8*)(Bb + (long)(n0 + row) * ldb + k0 + cg * 8);
    }
    __syncthreads();
#pragma unroll
    for (int kk = 0; kk < 2; ++kk) {
      bf16x8 af[4], bfr[4];
#pragma unroll
      for (int i = 0; i < 4; ++i) {
        int ar = wr + i * 16 + lrow;
        af[i] = *(const bf16x8*)&As[ar * 64 + ((((kk << 2) | lk) ^ (ar & 7)) << 3)];
        int br = wc + i * 16 + lrow;
        bfr[i] = *(const bf16x8*)&Bs[br * 64 + ((((kk << 2) | lk) ^ (br & 7)) << 3)];
      }
#pragma unroll
      for (int i = 0; i < 4; ++i)
#pragma unroll
        for (int j = 0; j < 4; ++j)
          acc[i][j] = __builtin_amdgcn_mfma_f32_16x16x32_bf16(af[i], bfr[j], acc[i][j], 0, 0, 0);
    }
  }

  const long coff = offs.c[z];
#pragma unroll
  for (int i = 0; i < 4; ++i)
#pragma unroll
    for (int j = 0; j < 4; ++j)
#pragma unroll
      for (int r = 0; r < 4; ++r) {
        int row = m0 + wr + i * 16 + lk * 4 + r;
        int col = n0 + wc + j * 16 + lrow;
        float v = acc[i][j][r];
        if (BIAS_MODE == 1) v += bias[col];
        if (BIAS_MODE == 2) v += bias[(row >> 11) * ldc + col];
        if (OUT_F32)
          ((float*)Cv)[coff + (long)row * ldc + col] = v;
        else
          ((u16*)Cv)[coff + (long)row * ldc + col] = f2b(v);
      }
}

// ---------------- flash attention ----------------
// grid (B, H, T/128); 256 thr, 4 waves; each wave owns 32 Q rows.
__global__ __launch_bounds__(256)
void fa_k(const u16* __restrict__ qkm, const u16* __restrict__ qkvT,
          const float* __restrict__ rel, const int* __restrict__ flags,
          u16* __restrict__ localf) {
  const int b = blockIdx.x, h = blockIdx.y;
  const int t0 = blockIdx.z * 128;
  const int t = threadIdx.x, w = t >> 6, l = t & 63;
  const int lrow = l & 15, lk = l >> 4;
  __shared__ u16 Qs[128 * 64];  // reused as per-wave P tiles after Q->regs
  __shared__ u16 Ks[64 * 64];
  __shared__ u16 Vs[64 * 64];

  const bool has_bias = (flags[h] != 0);
  const u16* qm = qkm + (long)(b * 2) * (2048 * 1024);
  const u16* km = qkm + (long)(b * 2 + 1) * (2048 * 1024);

  for (int ch = t; ch < 1024; ch += 256) {
    int r = ch >> 3, cg = ch & 7;
    *(bf16x8*)&Qs[r * 64 + ((cg ^ (r & 7)) << 3)] =
        *(const bf16x8*)(qm + (long)(t0 + r) * 1024 + h * 64 + cg * 8);
  }
  __syncthreads();
  bf16x8 qf[2][2];
#pragma unroll
  for (int i = 0; i < 2; ++i)
#pragma unroll
    for (int kk = 0; kk < 2; ++kk) {
      int r = w * 32 + i * 16 + lrow;
      qf[i][kk] = *(const bf16x8*)&Qs[r * 64 + ((((kk << 2) | lk) ^ (r & 7)) << 3)];
    }
  u16* Ps = Qs + w * (32 * 64);

  f32x4 o[2][4] = {};
  float mrun[2][4], lrun[2][4];
#pragma unroll
  for (int i = 0; i < 2; ++i)
#pragma unroll
    for (int r = 0; r < 4; ++r) { mrun[i][r] = -1e30f; lrun[i][r] = 0.f; }

  for (int s0 = 0; s0 < 2048; s0 += 64) {
    __syncthreads();
    for (int ch = t; ch < 512; ch += 256) {
      int r = ch >> 3, cg = ch & 7;
      int slot = r * 64 + ((cg ^ (r & 7)) << 3);
      *(bf16x8*)&Ks[slot] =
          *(const bf16x8*)(km + (long)(s0 + r) * 1024 + h * 64 + cg * 8);
      *(bf16x8*)&Vs[slot] =
          *(const bf16x8*)(qkvT + ((long)b * 3072 + 2048 + h * 64 + r) * 2048 + s0 + cg * 8);
    }
    __syncthreads();

    f32x4 sa[2][4] = {};
#pragma unroll
    for (int kk = 0; kk < 2; ++kk) {
      bf16x8 kf[4];
#pragma unroll
      for (int j = 0; j < 4; ++j) {
        int r = j * 16 + lrow;
        kf[j] = *(const bf16x8*)&Ks[r * 64 + ((((kk << 2) | lk) ^ (r & 7)) << 3)];
      }
#pragma unroll
      for (int i = 0; i < 2; ++i)
#pragma unroll
        for (int j = 0; j < 4; ++j)
          sa[i][j] = __builtin_amdgcn_mfma_f32_16x16x32_bf16(qf[i][kk], kf[j], sa[i][j], 0, 0, 0);
    }

    float pv[2][4][4];
#pragma unroll
    for (int i = 0; i < 2; ++i)
#pragma unroll
      for (int j = 0; j < 4; ++j)
#pragma unroll
        for (int r = 0; r < 4; ++r) {
          float v = sa[i][j][r] * 0.125f;
          if (has_bias)
            v += rel[((long)h * 2048 + t0 + w * 32 + i * 16 + lk * 4 + r) * 2048
                     + s0 + j * 16 + lrow];
          pv[i][j][r] = v;
        }

#pragma unroll
    for (int i = 0; i < 2; ++i)
#pragma unroll
      for (int r = 0; r < 4; ++r) {
        float mx = fmaxf(fmaxf(pv[i][0][r], pv[i][1][r]), fmaxf(pv[i][2][r], pv[i][3][r]));
        mx = fmaxf(mx, __shfl_xor(mx, 1));
        mx = fmaxf(mx, __shfl_xor(mx, 2));
        mx = fmaxf(mx, __shfl_xor(mx, 4));
        mx = fmaxf(mx, __shfl_xor(mx, 8));
        float mnew = fmaxf(mrun[i][r], mx);
        float sf = __expf(mrun[i][r] - mnew);
        float rs = 0.f;
#pragma unroll
        for (int j = 0; j < 4; ++j) {
          float p = __expf(pv[i][j][r] - mnew);
          pv[i][j][r] = p;
          rs += p;
        }
        rs += __shfl_xor(rs, 1);
        rs += __shfl_xor(rs, 2);
        rs += __shfl_xor(rs, 4);
        rs += __shfl_xor(rs, 8);
        lrun[i][r] = lrun[i][r] * sf + rs;
        mrun[i][r] = mnew;
#pragma unroll
        for (int j = 0; j < 4; ++j) o[i][j][r] *= sf;
      }

#pragma unroll
    for (int i = 0; i < 2; ++i)
#pragma unroll
      for (int j = 0; j < 4; ++j)
#pragma unroll
        for (int r = 0; r < 4; ++r) {
          int rp = i * 16 + lk * 4 + r, cp = j * 16 + lrow;
          Ps[rp * 64 + (((cp >> 3) ^ (rp & 7)) << 3) + (cp & 7)] = f2b(pv[i][j][r]);
        }
    __syncthreads();

#pragma unroll
    for (int kk = 0; kk < 2; ++kk) {
      bf16x8 pf[2], vf[4];
#pragma unroll
      for (int i = 0; i < 2; ++i) {
        int r = i * 16 + lrow;
        pf[i] = *(const bf16x8*)&Ps[r * 64 + ((((kk << 2) | lk) ^ (r & 7)) << 3)];
      }
#pragma unroll
      for (int j = 0; j < 4; ++j) {
        int r = j * 16 + lrow;
        vf[j] = *(const bf16x8*)&Vs[r * 64 + ((((kk << 2) | lk) ^ (r & 7)) << 3)];
      }
#pragma unroll
      for (int i = 0; i < 2; ++i)
#pragma unroll
        for (int j = 0; j < 4; ++j)
          o[i][j] = __builtin_amdgcn_mfma_f32_16x16x32_bf16(pf[i], vf[j], o[i][j], 0, 0, 0);
    }
  }

#pragma unroll
  for (int i = 0; i < 2; ++i)
#pragma unroll
    for (int j = 0; j < 4; ++j)
#pragma unroll
      for (int r = 0; r < 4; ++r) {
        float val = o[i][j][r] / lrun[i][r];
        localf[((long)b * 2048 + t0 + w * 32 + i * 16 + lk * 4 + r) * 1024
               + h * 64 + j * 16 + lrow] = f2b(val);
      }
}

// ---------------- latent path (tiny) ----------------
__global__ void latent_k(const u16* __restrict__ qkv, const float* __restrict__ W_lat,
                         const float* __restrict__ b_lat, const float* __restrict__ W_fuse,
                         const float* __restrict__ b_fuse, float* __restrict__ lat_term) {
  int bh = blockIdx.x, b = bh >> 4, h = bh & 15;
  int d = threadIdx.x;  // 64 threads
  float s = 0.f;
  for (int tt = 0; tt < 2048; ++tt)
    s += b2f(qkv[((long)b * 2048 + tt) * 3072 + 2048 + h * 64 + d]);
  __shared__ float mv[64], lat[64];
  mv[d] = s * (1.f / 2048.f);
  __syncthreads();
  float acc = b_lat[d];
  for (int k = 0; k < 64; ++k) acc += mv[k] * W_lat[k * 64 + d];
  lat[d] = acc;
  __syncthreads();
  float acc2 = b_fuse[d];
  for (int k = 0; k < 64; ++k) acc2 += lat[k] * W_fuse[(64 + k) * 64 + d];
  lat_term[bh * 64 + d] = acc2;
}

__global__ void outconst_k(const float* __restrict__ lat_term, const float* __restrict__ W_proj,
                           const float* __restrict__ b_proj, float* __restrict__ out_const) {
  int b = blockIdx.x;
  int c = blockIdx.y * 256 + threadIdx.x;
  float acc = b_proj[c];
  for (int hd = 0; hd < 1024; ++hd)
    acc += lat_term[b * 1024 + hd] * W_proj[(long)hd * 1024 + c];
  out_const[b * 1024 + c] = acc;
}

// WcombT[c][h*64+d0] = sum_d1 W_fuse[d0][d1] * W_proj[h*64+d1][c]
__global__ void wcombT_k(const float* __restrict__ W_fuse, const float* __restrict__ W_proj,
                         u16* __restrict__ WcombT) {
  long idx = (long)blockIdx.x * 256 + threadIdx.x;  // 1048576
  int c = (int)(idx >> 10), hd0 = (int)(idx & 1023);
  int h = hd0 >> 6, d0 = hd0 & 63;
  float acc = 0.f;
  for (int d1 = 0; d1 < 64; ++d1)
    acc += W_fuse[d0 * 64 + d1] * W_proj[(long)(h * 64 + d1) * 1024 + c];
  WcombT[(long)c * 1024 + hd0] = f2b(acc);
}

// ---------------- launch ----------------
extern "C" void kernel_launch(void* const* d_in, const int* in_sizes, int n_in,
                              void* d_out, int out_size, void* d_ws, size_t ws_size,
                              hipStream_t stream) {
  (void)in_sizes; (void)n_in; (void)out_size; (void)ws_size;
  const float* x      = (const float*)d_in[0];
  const float* W_attn = (const float*)d_in[1];
  const float* b_attn = (const float*)d_in[2];
  const float* W_proj = (const float*)d_in[3];
  const float* b_proj = (const float*)d_in[4];
  const float* rel    = (const float*)d_in[5];
  const float* alpha  = (const float*)d_in[6];
  const float* W_lat  = (const float*)d_in[7];
  const float* b_lat  = (const float*)d_in[8];
  const float* W_fuse = (const float*)d_in[9];
  const float* b_fuse = (const float*)d_in[10];
  float* out = (float*)d_out;
  char* ws = (char*)d_ws;

  // workspace layout (bytes); lifetime-safe reuse
  u16*   qkv      = (u16*)(ws + 0);          // [4096][3072] bf16 (dead after latent_k)
  u16*   localf   = (u16*)(ws + 0);          // [4096][1024] bf16 (written by fa_k)
  u16*   WcombT   = (u16*)(ws + 16777216);   // [1024][1024] bf16
  u16*   qkvT     = (u16*)(ws + 25165824);   // [2][3072][2048] bf16
  u16*   xb       = (u16*)(ws + 50331648);   // [4096][1024] bf16 (dead after G1)
  u16*   Hb       = (u16*)(ws + 50331648);   // [2048][2048] bf16 (after xb dead)
  u16*   WaT      = (u16*)(ws + 58720256);   // [3072][1024] bf16 (dead after G1)
  u16*   qkm      = (u16*)(ws + 58720256);   // [4][2048][1024] bf16 (after WaT dead)
  float* hbuf     = (float*)(ws + 75497472);
  float* lat_term = (float*)(ws + 75505664);
  float* out_const= (float*)(ws + 75513856);
  int*   flags    = (int*)(ws + 75522048);

  zero_flags_k<<<1, 64, 0, stream>>>(flags);
  bias_scan_k<<<1024, 256, 0, stream>>>(rel, flags);

  cvt_f2b_k<<<4096, 256, 0, stream>>>(x, xb);                       // x -> bf16
  transpose_f2b_k<<<dim3(48, 16), 256, 0, stream>>>(W_attn, WaT, 1024, 3072);

  GemmOffsets g0; for (int i = 0; i < 4; ++i) { g0.a[i]=0; g0.b[i]=0; g0.c[i]=0; }
  // G1: qkv = x @ W_attn + b_attn   [4096,1024]@[1024,3072]
  gemm_bt_k<1, false><<<dim3(24, 32, 1), 256, 0, stream>>>(
      xb, 1024, WaT, 1024, (void*)qkv, 3072, 1024, b_attn, g0);

  // qkvT[b][c][t] = qkv[b][t][c]
  transpose_b2b_k<<<dim3(48, 32, 2), 256, 0, stream>>>(qkv, qkvT, 2048, 3072);

  conv_h_k<<<8, 256, 0, stream>>>(alpha, hbuf);
  hb_fill_k<<<16384, 256, 0, stream>>>(hbuf, Hb);

  // G2: qkm[z] = Hb @ (q|k)[b]   z = b*2 + (0:q,1:k); [2048,2048]@[2048,1024]
  GemmOffsets g2;
  for (int i = 0; i < 4; ++i) g2.a[i] = 0;
  g2.b[0] = 0L;            g2.b[1] = 1024L * 2048;
  g2.b[2] = 3072L * 2048;  g2.b[3] = 4096L * 2048;
  g2.c[0] = 0L; g2.c[1] = 2097152L; g2.c[2] = 4194304L; g2.c[3] = 6291456L;
  gemm_bt_k<0, false><<<dim3(8, 16, 4), 256, 0, stream>>>(
      Hb, 2048, qkvT, 2048, (void*)qkm, 1024, 2048, nullptr, g2);

  latent_k<<<32, 64, 0, stream>>>(qkv, W_lat, b_lat, W_fuse, b_fuse, lat_term);
  outconst_k<<<dim3(2, 4), 256, 0, stream>>>(lat_term, W_proj, b_proj, out_const);
  wcombT_k<<<4096, 256, 0, stream>>>(W_fuse, W_proj, WcombT);

  // flash attention -> localf [4096][1024]
  fa_k<<<dim3(2, 16, 16), 256, 0, stream>>>(qkm, qkvT, rel, flags, localf);

  // G3: out = localf @ WcombT^T + out_const[b]   [4096,1024]@[1024,1024]
  gemm_bt_k<2, true><<<dim3(8, 32, 1), 256, 0, stream>>>(
      localf, 1024, WcombT, 1024, (void*)out, 1024, 1024, out_const, g0);
}

// Round 2
// 498.440 us; speedup vs baseline: 1.6228x; 1.6228x over previous
//
#include <hip/hip_runtime.h>

typedef unsigned short u16;
typedef __attribute__((ext_vector_type(8))) short bf16x8;
typedef __attribute__((ext_vector_type(4))) float f32x4;
typedef __attribute__((ext_vector_type(4))) unsigned short u16x4;

__device__ __forceinline__ u16 f2b(float f) {
  union { float f; unsigned u; } x; x.f = f;
  unsigned u = x.u;
  return (u16)((u + 0x7fffu + ((u >> 16) & 1u)) >> 16);
}
__device__ __forceinline__ float b2f(u16 b) {
  union { unsigned u; float f; } x; x.u = ((unsigned)b) << 16;
  return x.f;
}

struct GemmOffsets { long a[4]; long b[4]; long c[4]; };

// ---------------- tiny prep kernels ----------------
__global__ void zero_flags_k(int* flags) {
  if (threadIdx.x < 16) flags[threadIdx.x] = 0;
}

// per-head all-zero detection for rel_bias (correct for ANY input)
__global__ void bias_scan_k(const float* __restrict__ rel, int* __restrict__ flags) {
  long base = (long)blockIdx.x * 65536;
  int h = blockIdx.x >> 6;  // 64 blocks per head (head = 2048*2048 floats)
  const float4* p = (const float4*)(rel + base);
  bool nz = false;
  for (int i = threadIdx.x; i < 16384; i += 256) {
    float4 v = p[i];
    nz = nz || (v.x != 0.f) || (v.y != 0.f) || (v.z != 0.f) || (v.w != 0.f);
  }
  if (nz) atomicOr(flags + h, 1);
}

__global__ void cvt_f2b_k(const float* __restrict__ in, u16* __restrict__ out) {
  long i = ((long)blockIdx.x * 256 + threadIdx.x) * 4;
  float4 v = *(const float4*)(in + i);
  u16x4 o;
  o[0] = f2b(v.x); o[1] = f2b(v.y); o[2] = f2b(v.z); o[3] = f2b(v.w);
  *(u16x4*)(out + i) = o;
}

// out[c][r] = in[r][c]; f32 -> bf16. grid (C/64, R/64), 256 thr
__global__ void transpose_f2b_k(const float* __restrict__ in, u16* __restrict__ out,
                                int R, int C) {
  __shared__ float tile[64][68];
  int r0 = blockIdx.y * 64, c0 = blockIdx.x * 64;
  int t = threadIdx.x;
  for (int ch = t; ch < 1024; ch += 256) {
    int r = ch >> 4, q = ch & 15;
    float4 v = *(const float4*)(in + (long)(r0 + r) * C + c0 + q * 4);
    tile[r][q * 4 + 0] = v.x; tile[r][q * 4 + 1] = v.y;
    tile[r][q * 4 + 2] = v.z; tile[r][q * 4 + 3] = v.w;
  }
  __syncthreads();
  for (int ch = t; ch < 1024; ch += 256) {
    int cc = ch >> 4, g = ch & 15;
    u16x4 o;
    o[0] = f2b(tile[g * 4 + 0][cc]); o[1] = f2b(tile[g * 4 + 1][cc]);
    o[2] = f2b(tile[g * 4 + 2][cc]); o[3] = f2b(tile[g * 4 + 3][cc]);
    *(u16x4*)(out + (long)(c0 + cc) * R + r0 + g * 4) = o;
  }
}

// out[z][c][r] = in[z][r][c]; bf16. grid (C/64, R/64, Z), 256 thr
__global__ void transpose_b2b_k(const u16* __restrict__ in, u16* __restrict__ out,
                                int R, int C) {
  __shared__ u16 tile[64][80];
  long zb = (long)blockIdx.z * R * C;
  int r0 = blockIdx.y * 64, c0 = blockIdx.x * 64;
  int t = threadIdx.x;
  for (int ch = t; ch < 512; ch += 256) {
    int r = ch >> 3, q = ch & 7;
    *(bf16x8*)&tile[r][q * 8] =
        *(const bf16x8*)(in + zb + (long)(r0 + r) * C + c0 + q * 8);
  }
  __syncthreads();
  for (int ch = t; ch < 512; ch += 256) {
    int cc = ch >> 3, q = ch & 7;
    bf16x8 v;
#pragma unroll
    for (int k = 0; k < 8; ++k) v[k] = (short)tile[q * 8 + k][cc];
    *(bf16x8*)(out + zb + (long)(c0 + cc) * R + r0 + q * 8) = v;
  }
}

// h = irfft(exp(-j*alpha), n=2048): direct cosine sum with exact integer phase.
// one block per output tt; 256-thread reduction over j.
__global__ void conv_h_k(const float* __restrict__ alpha, float* __restrict__ hbuf) {
  int tt = blockIdx.x;   // 0..2047
  int t = threadIdx.x;   // 256
  float a = alpha[0];
  const float wph = 3.14159265358979323846f / 1024.f;
  float acc = 0.f;
  for (int j = 1 + t; j < 1024; j += 256) {
    int ph = (j * tt) & 2047;
    acc += 2.f * __expf(-a * (float)j) * __cosf((float)ph * wph);
  }
  if (t == 0) {
    acc += 1.0f;  // j = 0 term
    int ph = (1024 * tt) & 2047;
    acc += __expf(-a * 1024.f) * __cosf((float)ph * wph);
  }
  __shared__ float red[256];
  red[t] = acc;
  __syncthreads();
  for (int s = 128; s > 0; s >>= 1) {
    if (t < s) red[t] += red[t + s];
    __syncthreads();
  }
  if (t == 0) hbuf[tt] = red[0] * (1.f / 2048.f);
}

__global__ void hb_fill_k(const float* __restrict__ hbuf, u16* __restrict__ Hb) {
  long idx = (long)blockIdx.x * 256 + threadIdx.x;  // < 2048*2048
  int tt = (int)(idx >> 11), u = (int)(idx & 2047);
  Hb[idx] = f2b(hbuf[(tt - u) & 2047]);
}

// ---------------- shared bf16 MFMA GEMM: C = A[M,K] @ Bt[N,K]^T ----------------
// 128x128 tile, BK=64, 4 waves, XOR-swizzled LDS (16B chunk ^ (row&7)).
// BIAS_MODE: 0 none, 1 bias[col], 2 bias[(row>>11)*ldc+col]
template<int BIAS_MODE, bool OUT_F32>
__global__ __launch_bounds__(256)
void gemm_bt_k(const u16* __restrict__ A, int lda,
               const u16* __restrict__ Bt, int ldb,
               void* __restrict__ Cv, int ldc, int K,
               const float* __restrict__ bias, GemmOffsets offs) {
  __shared__ u16 As[128 * 64];
  __shared__ u16 Bs[128 * 64];
  const int z = blockIdx.z;
  const u16* Ab = A + offs.a[z];
  const u16* Bb = Bt + offs.b[z];
  const int m0 = blockIdx.y * 128, n0 = blockIdx.x * 128;
  const int t = threadIdx.x;
  const int w = t >> 6, l = t & 63;
  const int wr = (w >> 1) * 64, wc = (w & 1) * 64;
  const int lrow = l & 15, lk = l >> 4;

  f32x4 acc[4][4] = {};

  for (int k0 = 0; k0 < K; k0 += 64) {
    __syncthreads();
    for (int ch = t; ch < 1024; ch += 256) {
      int row = ch >> 3, cg = ch & 7;
      int slot = row * 64 + ((cg ^ (row & 7)) << 3);
      *(bf16x8*)&As[slot] = *(const bf16x8*)(Ab + (long)(m0 + row) * lda + k0 + cg * 8);
      *(bf16x8*)&Bs[slot] = *(const bf16x8*)(Bb + (long)(n0 + row) * ldb + k0 + cg * 8);
    }
    __syncthreads();
#pragma unroll
    for (int kk = 0; kk < 2; ++kk) {
      bf16x8 af[4], bfr[4];
#pragma unroll
      for (int i = 0; i < 4; ++i) {
        int ar = wr + i * 16 + lrow;
        af[i] = *(const bf16x8*)&As[ar * 64 + ((((kk << 2) | lk) ^ (ar & 7)) << 3)];
        int br = wc + i * 16 + lrow;
        bfr[i] = *(const bf16x8*)&Bs[br * 64 + ((((kk << 2) | lk) ^ (br & 7)) << 3)];
      }
#pragma unroll
      for (int i = 0; i < 4; ++i)
#pragma unroll
        for (int j = 0; j < 4; ++j)
          acc[i][j] = __builtin_amdgcn_mfma_f32_16x16x32_bf16(af[i], bfr[j], acc[i][j], 0, 0, 0);
    }
  }

  const long coff = offs.c[z];
#pragma unroll
  for (int i = 0; i < 4; ++i)
#pragma unroll
    for (int j = 0; j < 4; ++j)
#pragma unroll
      for (int r = 0; r < 4; ++r) {
        int row = m0 + wr + i * 16 + lk * 4 + r;
        int col = n0 + wc + j * 16 + lrow;
        float v = acc[i][j][r];
        if (BIAS_MODE == 1) v += bias[col];
        if (BIAS_MODE == 2) v += bias[(row >> 11) * ldc + col];
        if (OUT_F32)
          ((float*)Cv)[coff + (long)row * ldc + col] = v;
        else
          ((u16*)Cv)[coff + (long)row * ldc + col] = f2b(v);
      }
}

// ---------------- flash attention ----------------
// grid (B, H, T/128); 256 thr, 4 waves; each wave owns 32 Q rows.
__global__ __launch_bounds__(256)
void fa_k(const u16* __restrict__ qkm, const u16* __restrict__ qkvT,
          const float* __restrict__ rel, const int* __restrict__ flags,
          u16* __restrict__ localf) {
  const int b = blockIdx.x, h = blockIdx.y;
  const int t0 = blockIdx.z * 128;
  const int t = threadIdx.x, w = t >> 6, l = t & 63;
  const int lrow = l & 15, lk = l >> 4;
  __shared__ u16 Qs[128 * 64];  // reused as per-wave P tiles after Q->regs
  __shared__ u16 Ks[64 * 64];
  __shared__ u16 Vs[64 * 64];

  const bool has_bias = (flags[h] != 0);
  const u16* qm = qkm + (long)(b * 2) * (2048 * 1024);
  const u16* km = qkm + (long)(b * 2 + 1) * (2048 * 1024);

  for (int ch = t; ch < 1024; ch += 256) {
    int r = ch >> 3, cg = ch & 7;
    *(bf16x8*)&Qs[r * 64 + ((cg ^ (r & 7)) << 3)] =
        *(const bf16x8*)(qm + (long)(t0 + r) * 1024 + h * 64 + cg * 8);
  }
  __syncthreads();
  bf16x8 qf[2][2];
#pragma unroll
  for (int i = 0; i < 2; ++i)
#pragma unroll
    for (int kk = 0; kk < 2; ++kk) {
      int r = w * 32 + i * 16 + lrow;
      qf[i][kk] = *(const bf16x8*)&Qs[r * 64 + ((((kk << 2) | lk) ^ (r & 7)) << 3)];
    }
  u16* Ps = Qs + w * (32 * 64);

  f32x4 o[2][4] = {};
  float mrun[2][4], lrun[2][4];
#pragma unroll
  for (int i = 0; i < 2; ++i)
#pragma unroll
    for (int r = 0; r < 4; ++r) { mrun[i][r] = -1e30f; lrun[i][r] = 0.f; }

  for (int s0 = 0; s0 < 2048; s0 += 64) {
    __syncthreads();
    for (int ch = t; ch < 512; ch += 256) {
      int r = ch >> 3, cg = ch & 7;
      int slot = r * 64 + ((cg ^ (r & 7)) << 3);
      *(bf16x8*)&Ks[slot] =
          *(const bf16x8*)(km + (long)(s0 + r) * 1024 + h * 64 + cg * 8);
      *(bf16x8*)&Vs[slot] =
          *(const bf16x8*)(qkvT + ((long)b * 3072 + 2048 + h * 64 + r) * 2048 + s0 + cg * 8);
    }
    __syncthreads();

    f32x4 sa[2][4] = {};
#pragma unroll
    for (int kk = 0; kk < 2; ++kk) {
      bf16x8 kf[4];
#pragma unroll
      for (int j = 0; j < 4; ++j) {
        int r = j * 16 + lrow;
        kf[j] = *(const bf16x8*)&Ks[r * 64 + ((((kk << 2) | lk) ^ (r & 7)) << 3)];
      }
#pragma unroll
      for (int i = 0; i < 2; ++i)
#pragma unroll
        for (int j = 0; j < 4; ++j)
          sa[i][j] = __builtin_amdgcn_mfma_f32_16x16x32_bf16(qf[i][kk], kf[j], sa[i][j], 0, 0, 0);
    }

    float pv[2][4][4];
#pragma unroll
    for (int i = 0; i < 2; ++i)
#pragma unroll
      for (int j = 0; j < 4; ++j)
#pragma unroll
        for (int r = 0; r < 4; ++r) {
          float v = sa[i][j][r] * 0.125f;
          if (has_bias)
            v += rel[((long)h * 2048 + t0 + w * 32 + i * 16 + lk * 4 + r) * 2048
                     + s0 + j * 16 + lrow];
          pv[i][j][r] = v;
        }

#pragma unroll
    for (int i = 0; i < 2; ++i)
#pragma unroll
      for (int r = 0; r < 4; ++r) {
        float mx = fmaxf(fmaxf(pv[i][0][r], pv[i][1][r]), fmaxf(pv[i][2][r], pv[i][3][r]));
        mx = fmaxf(mx, __shfl_xor(mx, 1));
        mx = fmaxf(mx, __shfl_xor(mx, 2));
        mx = fmaxf(mx, __shfl_xor(mx, 4));
        mx = fmaxf(mx, __shfl_xor(mx, 8));
        float mnew = fmaxf(mrun[i][r], mx);
        float sf = __expf(mrun[i][r] - mnew);
        float rs = 0.f;
#pragma unroll
        for (int j = 0; j < 4; ++j) {
          float p = __expf(pv[i][j][r] - mnew);
          pv[i][j][r] = p;
          rs += p;
        }
        rs += __shfl_xor(rs, 1);
        rs += __shfl_xor(rs, 2);
        rs += __shfl_xor(rs, 4);
        rs += __shfl_xor(rs, 8);
        lrun[i][r] = lrun[i][r] * sf + rs;
        mrun[i][r] = mnew;
#pragma unroll
        for (int j = 0; j < 4; ++j) o[i][j][r] *= sf;
      }

#pragma unroll
    for (int i = 0; i < 2; ++i)
#pragma unroll
      for (int j = 0; j < 4; ++j)
#pragma unroll
        for (int r = 0; r < 4; ++r) {
          int rp = i * 16 + lk * 4 + r, cp = j * 16 + lrow;
          Ps[rp * 64 + (((cp >> 3) ^ (rp & 7)) << 3) + (cp & 7)] = f2b(pv[i][j][r]);
        }
    __syncthreads();

#pragma unroll
    for (int kk = 0; kk < 2; ++kk) {
      bf16x8 pf[2], vf[4];
#pragma unroll
      for (int i = 0; i < 2; ++i) {
        int r = i * 16 + lrow;
        pf[i] = *(const bf16x8*)&Ps[r * 64 + ((((kk << 2) | lk) ^ (r & 7)) << 3)];
      }
#pragma unroll
      for (int j = 0; j < 4; ++j) {
        int r = j * 16 + lrow;
        vf[j] = *(const bf16x8*)&Vs[r * 64 + ((((kk << 2) | lk) ^ (r & 7)) << 3)];
      }
#pragma unroll
      for (int i = 0; i < 2; ++i)
#pragma unroll
        for (int j = 0; j < 4; ++j)
          o[i][j] = __builtin_amdgcn_mfma_f32_16x16x32_bf16(pf[i], vf[j], o[i][j], 0, 0, 0);
    }
  }

#pragma unroll
  for (int i = 0; i < 2; ++i)
#pragma unroll
    for (int j = 0; j < 4; ++j)
#pragma unroll
      for (int r = 0; r < 4; ++r) {
        float val = o[i][j][r] / lrun[i][r];
        localf[((long)b * 2048 + t0 + w * 32 + i * 16 + lk * 4 + r) * 1024
               + h * 64 + j * 16 + lrow] = f2b(val);
      }
}

// ---------------- latent path: two-stage deterministic reduction ----------------
// stage 1: partial column sums of the v slice. grid (B, 16), 256 thr.
__global__ void vmean_part_k(const u16* __restrict__ qkv, float* __restrict__ part) {
  int b = blockIdx.x, ch = blockIdx.y;
  int t = threadIdx.x;
  int c0 = (t & 127) * 8;  // column group (1024 v-cols / 8)
  int rh = t >> 7;         // row half
  float acc[8] = {};
  for (int r = rh; r < 128; r += 2) {
    bf16x8 v = *(const bf16x8*)(qkv + ((long)b * 2048 + ch * 128 + r) * 3072 + 2048 + c0);
#pragma unroll
    for (int k = 0; k < 8; ++k) acc[k] += b2f((u16)(unsigned short)v[k]);
  }
  __shared__ float red[1024];
  if (rh == 1) {
#pragma unroll
    for (int k = 0; k < 8; ++k) red[c0 + k] = acc[k];
  }
  __syncthreads();
  if (rh == 0) {
#pragma unroll
    for (int k = 0; k < 8; ++k)
      part[((long)b * 16 + ch) * 1024 + c0 + k] = acc[k] + red[c0 + k];
  }
}

// stage 2: finish mean + W_lat + W_fuse[64:] chain. grid (B*H), 64 thr.
__global__ void latent2_k(const float* __restrict__ part, const float* __restrict__ W_lat,
                          const float* __restrict__ b_lat, const float* __restrict__ W_fuse,
                          const float* __restrict__ b_fuse, float* __restrict__ lat_term) {
  int bh = blockIdx.x, b = bh >> 4, h = bh & 15;
  int d = threadIdx.x;  // 64 threads
  float s = 0.f;
#pragma unroll
  for (int c = 0; c < 16; ++c) s += part[((long)b * 16 + c) * 1024 + h * 64 + d];
  __shared__ float mv[64], lat[64];
  mv[d] = s * (1.f / 2048.f);
  __syncthreads();
  float acc = b_lat[d];
  for (int k = 0; k < 64; ++k) acc += mv[k] * W_lat[k * 64 + d];
  lat[d] = acc;
  __syncthreads();
  float acc2 = b_fuse[d];
  for (int k = 0; k < 64; ++k) acc2 += lat[k] * W_fuse[(64 + k) * 64 + d];
  lat_term[bh * 64 + d] = acc2;
}

__global__ void outconst_k(const float* __restrict__ lat_term, const float* __restrict__ W_proj,
                           const float* __restrict__ b_proj, float* __restrict__ out_const) {
  int b = blockIdx.x;
  int c = blockIdx.y * 256 + threadIdx.x;
  float acc = b_proj[c];
  for (int hd = 0; hd < 1024; ++hd)
    acc += lat_term[b * 1024 + hd] * W_proj[(long)hd * 1024 + c];
  out_const[b * 1024 + c] = acc;
}

// WcombT[c][h*64+d0] = sum_d1 W_fuse[d0][d1] * W_proj[h*64+d1][c]
__global__ void wcombT_k(const float* __restrict__ W_fuse, const float* __restrict__ W_proj,
                         u16* __restrict__ WcombT) {
  long idx = (long)blockIdx.x * 256 + threadIdx.x;  // 1048576
  int c = (int)(idx >> 10), hd0 = (int)(idx & 1023);
  int h = hd0 >> 6, d0 = hd0 & 63;
  float acc = 0.f;
  for (int d1 = 0; d1 < 64; ++d1)
    acc += W_fuse[d0 * 64 + d1] * W_proj[(long)(h * 64 + d1) * 1024 + c];
  WcombT[(long)c * 1024 + hd0] = f2b(acc);
}

// ---------------- launch ----------------
extern "C" void kernel_launch(void* const* d_in, const int* in_sizes, int n_in,
                              void* d_out, int out_size, void* d_ws, size_t ws_size,
                              hipStream_t stream) {
  (void)in_sizes; (void)n_in; (void)out_size; (void)ws_size;
  const float* x      = (const float*)d_in[0];
  const float* W_attn = (const float*)d_in[1];
  const float* b_attn = (const float*)d_in[2];
  const float* W_proj = (const float*)d_in[3];
  const float* b_proj = (const float*)d_in[4];
  const float* rel    = (const float*)d_in[5];
  const float* alpha  = (const float*)d_in[6];
  const float* W_lat  = (const float*)d_in[7];
  const float* b_lat  = (const float*)d_in[8];
  const float* W_fuse = (const float*)d_in[9];
  const float* b_fuse = (const float*)d_in[10];
  float* out = (float*)d_out;
  char* ws = (char*)d_ws;

  // workspace layout (bytes); lifetime-safe reuse
  u16*   qkv      = (u16*)(ws + 0);          // [4096][3072] bf16 (dead after vmean_part_k)
  u16*   localf   = (u16*)(ws + 0);          // [4096][1024] bf16 (written by fa_k)
  u16*   WcombT   = (u16*)(ws + 16777216);   // [1024][1024] bf16
  u16*   qkvT     = (u16*)(ws + 25165824);   // [2][3072][2048] bf16
  u16*   xb       = (u16*)(ws + 50331648);   // [4096][1024] bf16 (dead after G1)
  u16*   Hb       = (u16*)(ws + 50331648);   // [2048][2048] bf16 (after xb dead)
  u16*   WaT      = (u16*)(ws + 58720256);   // [3072][1024] bf16 (dead after G1)
  u16*   qkm      = (u16*)(ws + 58720256);   // [4][2048][1024] bf16 (after WaT dead)
  float* hbuf     = (float*)(ws + 75497472);
  float* lat_term = (float*)(ws + 75505664);
  float* out_const= (float*)(ws + 75513856);
  int*   flags    = (int*)(ws + 75522048);
  float* part     = (float*)(ws + 75522304); // [2][16][1024] f32 partial sums

  zero_flags_k<<<1, 64, 0, stream>>>(flags);
  bias_scan_k<<<1024, 256, 0, stream>>>(rel, flags);

  cvt_f2b_k<<<4096, 256, 0, stream>>>(x, xb);                       // x -> bf16
  transpose_f2b_k<<<dim3(48, 16), 256, 0, stream>>>(W_attn, WaT, 1024, 3072);

  GemmOffsets g0; for (int i = 0; i < 4; ++i) { g0.a[i]=0; g0.b[i]=0; g0.c[i]=0; }
  // G1: qkv = x @ W_attn + b_attn   [4096,1024]@[1024,3072]
  gemm_bt_k<1, false><<<dim3(24, 32, 1), 256, 0, stream>>>(
      xb, 1024, WaT, 1024, (void*)qkv, 3072, 1024, b_attn, g0);

  // qkvT[b][c][t] = qkv[b][t][c]
  transpose_b2b_k<<<dim3(48, 32, 2), 256, 0, stream>>>(qkv, qkvT, 2048, 3072);

  conv_h_k<<<2048, 256, 0, stream>>>(alpha, hbuf);
  hb_fill_k<<<16384, 256, 0, stream>>>(hbuf, Hb);

  // G2: qkm[z] = Hb @ (q|k)[b]   z = b*2 + (0:q,1:k); [2048,2048]@[2048,1024]
  GemmOffsets g2;
  for (int i = 0; i < 4; ++i) g2.a[i] = 0;
  g2.b[0] = 0L;            g2.b[1] = 1024L * 2048;
  g2.b[2] = 3072L * 2048;  g2.b[3] = 4096L * 2048;
  g2.c[0] = 0L; g2.c[1] = 2097152L; g2.c[2] = 4194304L; g2.c[3] = 6291456L;
  gemm_bt_k<0, false><<<dim3(8, 16, 4), 256, 0, stream>>>(
      Hb, 2048, qkvT, 2048, (void*)qkm, 1024, 2048, nullptr, g2);

  // latent path (parallel two-stage reduction)
  vmean_part_k<<<dim3(2, 16), 256, 0, stream>>>(qkv, part);
  latent2_k<<<32, 64, 0, stream>>>(part, W_lat, b_lat, W_fuse, b_fuse, lat_term);
  outconst_k<<<dim3(2, 4), 256, 0, stream>>>(lat_term, W_proj, b_proj, out_const);
  wcombT_k<<<4096, 256, 0, stream>>>(W_fuse, W_proj, WcombT);

  // flash attention -> localf [4096][1024]
  fa_k<<<dim3(2, 16, 16), 256, 0, stream>>>(qkm, qkvT, rel, flags, localf);

  // G3: out = localf @ WcombT^T + out_const[b]   [4096,1024]@[1024,1024]
  gemm_bt_k<2, true><<<dim3(8, 32, 1), 256, 0, stream>>>(
      localf, 1024, WcombT, 1024, (void*)out, 1024, 1024, out_const, g0);
}

// Round 3
// 472.362 us; speedup vs baseline: 1.7124x; 1.0552x over previous
//
#include <hip/hip_runtime.h>

typedef unsigned short u16;
typedef __attribute__((ext_vector_type(8))) short bf16x8;
typedef __attribute__((ext_vector_type(4))) float f32x4;
typedef __attribute__((ext_vector_type(4))) unsigned short u16x4;

__device__ __forceinline__ u16 f2b(float f) {
  union { float f; unsigned u; } x; x.f = f;
  unsigned u = x.u;
  return (u16)((u + 0x7fffu + ((u >> 16) & 1u)) >> 16);
}
__device__ __forceinline__ float b2f(u16 b) {
  union { unsigned u; float f; } x; x.u = ((unsigned)b) << 16;
  return x.f;
}

struct GemmOffsets { long a[4]; long b[4]; long c[4]; };

// ---------------- tiny prep kernels ----------------
__global__ void zero_flags_k(int* flags) {
  if (threadIdx.x < 16) flags[threadIdx.x] = 0;
}

// per-head all-zero detection for rel_bias (correct for ANY input)
__global__ void bias_scan_k(const float* __restrict__ rel, int* __restrict__ flags) {
  long base = (long)blockIdx.x * 65536;
  int h = blockIdx.x >> 6;  // 64 blocks per head (head = 2048*2048 floats)
  const float4* p = (const float4*)(rel + base);
  bool nz = false;
  for (int i = threadIdx.x; i < 16384; i += 256) {
    float4 v = p[i];
    nz = nz || (v.x != 0.f) || (v.y != 0.f) || (v.z != 0.f) || (v.w != 0.f);
  }
  if (nz) atomicOr(flags + h, 1);
}

__global__ void cvt_f2b_k(const float* __restrict__ in, u16* __restrict__ out) {
  long i = ((long)blockIdx.x * 256 + threadIdx.x) * 4;
  float4 v = *(const float4*)(in + i);
  u16x4 o;
  o[0] = f2b(v.x); o[1] = f2b(v.y); o[2] = f2b(v.z); o[3] = f2b(v.w);
  *(u16x4*)(out + i) = o;
}

// out[c][r] = in[r][c]; f32 -> bf16. grid (C/64, R/64), 256 thr
__global__ void transpose_f2b_k(const float* __restrict__ in, u16* __restrict__ out,
                                int R, int C) {
  __shared__ float tile[64][68];
  int r0 = blockIdx.y * 64, c0 = blockIdx.x * 64;
  int t = threadIdx.x;
  for (int ch = t; ch < 1024; ch += 256) {
    int r = ch >> 4, q = ch & 15;
    float4 v = *(const float4*)(in + (long)(r0 + r) * C + c0 + q * 4);
    tile[r][q * 4 + 0] = v.x; tile[r][q * 4 + 1] = v.y;
    tile[r][q * 4 + 2] = v.z; tile[r][q * 4 + 3] = v.w;
  }
  __syncthreads();
  for (int ch = t; ch < 1024; ch += 256) {
    int cc = ch >> 4, g = ch & 15;
    u16x4 o;
    o[0] = f2b(tile[g * 4 + 0][cc]); o[1] = f2b(tile[g * 4 + 1][cc]);
    o[2] = f2b(tile[g * 4 + 2][cc]); o[3] = f2b(tile[g * 4 + 3][cc]);
    *(u16x4*)(out + (long)(c0 + cc) * R + r0 + g * 4) = o;
  }
}

// out[z][c][r] = in[z][r][c]; bf16. grid (C/64, R/64, Z), 256 thr
__global__ void transpose_b2b_k(const u16* __restrict__ in, u16* __restrict__ out,
                                int R, int C) {
  __shared__ u16 tile[64][80];
  long zb = (long)blockIdx.z * R * C;
  int r0 = blockIdx.y * 64, c0 = blockIdx.x * 64;
  int t = threadIdx.x;
  for (int ch = t; ch < 512; ch += 256) {
    int r = ch >> 3, q = ch & 7;
    *(bf16x8*)&tile[r][q * 8] =
        *(const bf16x8*)(in + zb + (long)(r0 + r) * C + c0 + q * 8);
  }
  __syncthreads();
  for (int ch = t; ch < 512; ch += 256) {
    int cc = ch >> 3, q = ch & 7;
    bf16x8 v;
#pragma unroll
    for (int k = 0; k < 8; ++k) v[k] = (short)tile[q * 8 + k][cc];
    *(bf16x8*)(out + zb + (long)(c0 + cc) * R + r0 + q * 8) = v;
  }
}

// h = irfft(exp(-j*alpha), n=2048): direct cosine sum with exact integer phase.
// one block per output tt; 256-thread reduction over j.
__global__ void conv_h_k(const float* __restrict__ alpha, float* __restrict__ hbuf) {
  int tt = blockIdx.x;   // 0..2047
  int t = threadIdx.x;   // 256
  float a = alpha[0];
  const float wph = 3.14159265358979323846f / 1024.f;
  float acc = 0.f;
  for (int j = 1 + t; j < 1024; j += 256) {
    int ph = (j * tt) & 2047;
    acc += 2.f * __expf(-a * (float)j) * __cosf((float)ph * wph);
  }
  if (t == 0) {
    acc += 1.0f;  // j = 0 term
    int ph = (1024 * tt) & 2047;
    acc += __expf(-a * 1024.f) * __cosf((float)ph * wph);
  }
  __shared__ float red[256];
  red[t] = acc;
  __syncthreads();
  for (int s = 128; s > 0; s >>= 1) {
    if (t < s) red[t] += red[t + s];
    __syncthreads();
  }
  if (t == 0) hbuf[tt] = red[0] * (1.f / 2048.f);
}

__global__ void hb_fill_k(const float* __restrict__ hbuf, u16* __restrict__ Hb) {
  long idx = (long)blockIdx.x * 256 + threadIdx.x;  // < 2048*2048
  int tt = (int)(idx >> 11), u = (int)(idx & 2047);
  Hb[idx] = f2b(hbuf[(tt - u) & 2047]);
}

// ---------------- shared bf16 MFMA GEMM: C = A[M,K] @ Bt[N,K]^T ----------------
// 128x128 tile, BK=64, 4 waves, XOR-swizzled LDS (16B chunk ^ (row&7)).
// BIAS_MODE: 0 none, 1 bias[col], 2 bias[(row>>11)*ldc+col]
template<int BIAS_MODE, bool OUT_F32>
__global__ __launch_bounds__(256)
void gemm_bt_k(const u16* __restrict__ A, int lda,
               const u16* __restrict__ Bt, int ldb,
               void* __restrict__ Cv, int ldc, int K,
               const float* __restrict__ bias, GemmOffsets offs) {
  __shared__ u16 As[128 * 64];
  __shared__ u16 Bs[128 * 64];
  const int z = blockIdx.z;
  const u16* Ab = A + offs.a[z];
  const u16* Bb = Bt + offs.b[z];
  const int m0 = blockIdx.y * 128, n0 = blockIdx.x * 128;
  const int t = threadIdx.x;
  const int w = t >> 6, l = t & 63;
  const int wr = (w >> 1) * 64, wc = (w & 1) * 64;
  const int lrow = l & 15, lk = l >> 4;

  f32x4 acc[4][4] = {};

  for (int k0 = 0; k0 < K; k0 += 64) {
    __syncthreads();
    for (int ch = t; ch < 1024; ch += 256) {
      int row = ch >> 3, cg = ch & 7;
      int slot = row * 64 + ((cg ^ (row & 7)) << 3);
      *(bf16x8*)&As[slot] = *(const bf16x8*)(Ab + (long)(m0 + row) * lda + k0 + cg * 8);
      *(bf16x8*)&Bs[slot] = *(const bf16x8*)(Bb + (long)(n0 + row) * ldb + k0 + cg * 8);
    }
    __syncthreads();
#pragma unroll
    for (int kk = 0; kk < 2; ++kk) {
      bf16x8 af[4], bfr[4];
#pragma unroll
      for (int i = 0; i < 4; ++i) {
        int ar = wr + i * 16 + lrow;
        af[i] = *(const bf16x8*)&As[ar * 64 + ((((kk << 2) | lk) ^ (ar & 7)) << 3)];
        int br = wc + i * 16 + lrow;
        bfr[i] = *(const bf16x8*)&Bs[br * 64 + ((((kk << 2) | lk) ^ (br & 7)) << 3)];
      }
#pragma unroll
      for (int i = 0; i < 4; ++i)
#pragma unroll
        for (int j = 0; j < 4; ++j)
          acc[i][j] = __builtin_amdgcn_mfma_f32_16x16x32_bf16(af[i], bfr[j], acc[i][j], 0, 0, 0);
    }
  }

  const long coff = offs.c[z];
#pragma unroll
  for (int i = 0; i < 4; ++i)
#pragma unroll
    for (int j = 0; j < 4; ++j)
#pragma unroll
      for (int r = 0; r < 4; ++r) {
        int row = m0 + wr + i * 16 + lk * 4 + r;
        int col = n0 + wc + j * 16 + lrow;
        float v = acc[i][j][r];
        if (BIAS_MODE == 1) v += bias[col];
        if (BIAS_MODE == 2) v += bias[(row >> 11) * ldc + col];
        if (OUT_F32)
          ((float*)Cv)[coff + (long)row * ldc + col] = v;
        else
          ((u16*)Cv)[coff + (long)row * ldc + col] = f2b(v);
      }
}

// ---------------- flash attention v2 ----------------
// grid (B, H, T/128); 256 thr, 4 waves; each wave owns 32 Q rows.
// No-max softmax (clamped exp2), deferred sum reduction, padded per-wave P
// tile (stride 72 u16 -> imm-offset ds_write_b16), double-buffered K/V,
// 1 barrier per KV tile.
__global__ __launch_bounds__(256)
void fa_k(const u16* __restrict__ qkm, const u16* __restrict__ qkvT,
          const float* __restrict__ rel, const int* __restrict__ flags,
          u16* __restrict__ localf) {
  const int b = blockIdx.x, h = blockIdx.y;
  const int t0 = blockIdx.z * 128;
  const int t = threadIdx.x, w = t >> 6, l = t & 63;
  const int lrow = l & 15, lk = l >> 4;
  __shared__ u16 QPs[9216];      // Q staging (8192 u16), then per-wave P [32][72]
  __shared__ u16 Ks[2][64 * 64];
  __shared__ u16 Vs[2][64 * 64];

  const bool has_bias = (flags[h] != 0);
  const u16* qm = qkm + (long)(b * 2) * (2048 * 1024);
  const u16* km = qkm + (long)(b * 2 + 1) * (2048 * 1024);

  // stage Q tile (swizzled)
  for (int ch = t; ch < 1024; ch += 256) {
    int r = ch >> 3, cg = ch & 7;
    *(bf16x8*)&QPs[r * 64 + ((cg ^ (r & 7)) << 3)] =
        *(const bf16x8*)(qm + (long)(t0 + r) * 1024 + h * 64 + cg * 8);
  }
  // stage K/V tile 0 into buffer 0
  auto stage = [&](int tile, int buf) {
    int s0 = tile * 64;
    for (int ch = t; ch < 512; ch += 256) {
      int r = ch >> 3, cg = ch & 7;
      int slot = r * 64 + ((cg ^ (r & 7)) << 3);
      *(bf16x8*)&Ks[buf][slot] =
          *(const bf16x8*)(km + (long)(s0 + r) * 1024 + h * 64 + cg * 8);
      *(bf16x8*)&Vs[buf][slot] =
          *(const bf16x8*)(qkvT + ((long)b * 3072 + 2048 + h * 64 + r) * 2048 + s0 + cg * 8);
    }
  };
  stage(0, 0);
  __syncthreads();

  bf16x8 qf[2][2];
#pragma unroll
  for (int i = 0; i < 2; ++i)
#pragma unroll
    for (int kk = 0; kk < 2; ++kk) {
      int r = w * 32 + i * 16 + lrow;
      qf[i][kk] = *(const bf16x8*)&QPs[r * 64 + ((((kk << 2) | lk) ^ (r & 7)) << 3)];
    }
  __syncthreads();  // all waves done reading Q before any P store into QPs

  // per-wave padded P tile: rows stride 72 u16 (144 B, 16B-aligned rows)
  u16* Pw = QPs + w * 2304 + (lk * 4) * 72 + lrow;       // write base (+i*1152+r*72+j*16)
  const u16* Pr = QPs + w * 2304 + lrow * 72 + lk * 8;   // read base  (+i*1152+kk*32)

  f32x4 o[2][4] = {};
  float lsum[2][4] = {};

  for (int it = 0; it < 32; ++it) {
    const int cur = it & 1;
    const u16* Kb = Ks[cur];
    const u16* Vb = Vs[cur];

    // QK^T
    f32x4 sa[2][4] = {};
#pragma unroll
    for (int kk = 0; kk < 2; ++kk) {
      bf16x8 kf[4];
#pragma unroll
      for (int j = 0; j < 4; ++j) {
        int r = j * 16 + lrow;
        kf[j] = *(const bf16x8*)&Kb[r * 64 + ((((kk << 2) | lk) ^ (r & 7)) << 3)];
      }
#pragma unroll
      for (int i = 0; i < 2; ++i)
#pragma unroll
        for (int j = 0; j < 4; ++j)
          sa[i][j] = __builtin_amdgcn_mfma_f32_16x16x32_bf16(qf[i][kk], kf[j], sa[i][j], 0, 0, 0);
    }

    // prefetch next K/V tile (overlaps softmax + PV; drains at barrier)
    if (it < 31) stage(it + 1, cur ^ 1);

    // softmax-lite: p = exp2((S/8 + bias) * log2e), clamped; no max tracking
#pragma unroll
    for (int i = 0; i < 2; ++i)
#pragma unroll
      for (int j = 0; j < 4; ++j)
#pragma unroll
        for (int r = 0; r < 4; ++r) {
          float vv = sa[i][j][r] * 0.1803368867f;  // 0.125 * log2(e)
          if (has_bias)
            vv += 1.4426950409f *
                  rel[((long)h * 2048 + t0 + w * 32 + i * 16 + lk * 4 + r) * 2048
                      + it * 64 + j * 16 + lrow];
          float p = exp2f(fminf(vv, 86.0f));
          lsum[i][r] += p;
          Pw[i * 1152 + r * 72 + j * 16] = f2b(p);
        }

    // PV
#pragma unroll
    for (int kk = 0; kk < 2; ++kk) {
      bf16x8 pf[2], vf[4];
#pragma unroll
      for (int i = 0; i < 2; ++i)
        pf[i] = *(const bf16x8*)&Pr[i * 1152 + kk * 32];
#pragma unroll
      for (int j = 0; j < 4; ++j) {
        int r = j * 16 + lrow;
        vf[j] = *(const bf16x8*)&Vb[r * 64 + ((((kk << 2) | lk) ^ (r & 7)) << 3)];
      }
#pragma unroll
      for (int i = 0; i < 2; ++i)
#pragma unroll
        for (int j = 0; j < 4; ++j)
          o[i][j] = __builtin_amdgcn_mfma_f32_16x16x32_bf16(pf[i], vf[j], o[i][j], 0, 0, 0);
    }
    __syncthreads();  // staging done + all readers of cur done
  }

  // deferred denominator: reduce over the 16-lane key dimension, once
#pragma unroll
  for (int i = 0; i < 2; ++i)
#pragma unroll
    for (int r = 0; r < 4; ++r) {
      float s = lsum[i][r];
      s += __shfl_xor(s, 1);
      s += __shfl_xor(s, 2);
      s += __shfl_xor(s, 4);
      s += __shfl_xor(s, 8);
      float inv = 1.0f / s;
#pragma unroll
      for (int j = 0; j < 4; ++j)
        localf[((long)b * 2048 + t0 + w * 32 + i * 16 + lk * 4 + r) * 1024
               + h * 64 + j * 16 + lrow] = f2b(o[i][j][r] * inv);
    }
}

// ---------------- latent path: two-stage deterministic reduction ----------------
// stage 1: partial column sums of the v slice. grid (B, 16), 256 thr.
__global__ void vmean_part_k(const u16* __restrict__ qkv, float* __restrict__ part) {
  int b = blockIdx.x, ch = blockIdx.y;
  int t = threadIdx.x;
  int c0 = (t & 127) * 8;  // column group (1024 v-cols / 8)
  int rh = t >> 7;         // row half
  float acc[8] = {};
  for (int r = rh; r < 128; r += 2) {
    bf16x8 v = *(const bf16x8*)(qkv + ((long)b * 2048 + ch * 128 + r) * 3072 + 2048 + c0);
#pragma unroll
    for (int k = 0; k < 8; ++k) acc[k] += b2f((u16)(unsigned short)v[k]);
  }
  __shared__ float red[1024];
  if (rh == 1) {
#pragma unroll
    for (int k = 0; k < 8; ++k) red[c0 + k] = acc[k];
  }
  __syncthreads();
  if (rh == 0) {
#pragma unroll
    for (int k = 0; k < 8; ++k)
      part[((long)b * 16 + ch) * 1024 + c0 + k] = acc[k] + red[c0 + k];
  }
}

// stage 2: finish mean + W_lat + W_fuse[64:] chain. grid (B*H), 64 thr.
__global__ void latent2_k(const float* __restrict__ part, const float* __restrict__ W_lat,
                          const float* __restrict__ b_lat, const float* __restrict__ W_fuse,
                          const float* __restrict__ b_fuse, float* __restrict__ lat_term) {
  int bh = blockIdx.x, b = bh >> 4, h = bh & 15;
  int d = threadIdx.x;  // 64 threads
  float s = 0.f;
#pragma unroll
  for (int c = 0; c < 16; ++c) s += part[((long)b * 16 + c) * 1024 + h * 64 + d];
  __shared__ float mv[64], lat[64];
  mv[d] = s * (1.f / 2048.f);
  __syncthreads();
  float acc = b_lat[d];
  for (int k = 0; k < 64; ++k) acc += mv[k] * W_lat[k * 64 + d];
  lat[d] = acc;
  __syncthreads();
  float acc2 = b_fuse[d];
  for (int k = 0; k < 64; ++k) acc2 += lat[k] * W_fuse[(64 + k) * 64 + d];
  lat_term[bh * 64 + d] = acc2;
}

__global__ void outconst_k(const float* __restrict__ lat_term, const float* __restrict__ W_proj,
                           const float* __restrict__ b_proj, float* __restrict__ out_const) {
  int b = blockIdx.x;
  int c = blockIdx.y * 256 + threadIdx.x;
  float acc = b_proj[c];
  for (int hd = 0; hd < 1024; ++hd)
    acc += lat_term[b * 1024 + hd] * W_proj[(long)hd * 1024 + c];
  out_const[b * 1024 + c] = acc;
}

// WcombT[c][h*64+d0] = sum_d1 W_fuse[d0][d1] * W_proj[h*64+d1][c]
__global__ void wcombT_k(const float* __restrict__ W_fuse, const float* __restrict__ W_proj,
                         u16* __restrict__ WcombT) {
  long idx = (long)blockIdx.x * 256 + threadIdx.x;  // 1048576
  int c = (int)(idx >> 10), hd0 = (int)(idx & 1023);
  int h = hd0 >> 6, d0 = hd0 & 63;
  float acc = 0.f;
  for (int d1 = 0; d1 < 64; ++d1)
    acc += W_fuse[d0 * 64 + d1] * W_proj[(long)(h * 64 + d1) * 1024 + c];
  WcombT[(long)c * 1024 + hd0] = f2b(acc);
}

// ---------------- launch ----------------
extern "C" void kernel_launch(void* const* d_in, const int* in_sizes, int n_in,
                              void* d_out, int out_size, void* d_ws, size_t ws_size,
                              hipStream_t stream) {
  (void)in_sizes; (void)n_in; (void)out_size; (void)ws_size;
  const float* x      = (const float*)d_in[0];
  const float* W_attn = (const float*)d_in[1];
  const float* b_attn = (const float*)d_in[2];
  const float* W_proj = (const float*)d_in[3];
  const float* b_proj = (const float*)d_in[4];
  const float* rel    = (const float*)d_in[5];
  const float* alpha  = (const float*)d_in[6];
  const float* W_lat  = (const float*)d_in[7];
  const float* b_lat  = (const float*)d_in[8];
  const float* W_fuse = (const float*)d_in[9];
  const float* b_fuse = (const float*)d_in[10];
  float* out = (float*)d_out;
  char* ws = (char*)d_ws;

  // workspace layout (bytes); lifetime-safe reuse
  u16*   qkv      = (u16*)(ws + 0);          // [4096][3072] bf16 (dead after vmean_part_k)
  u16*   localf   = (u16*)(ws + 0);          // [4096][1024] bf16 (written by fa_k)
  u16*   WcombT   = (u16*)(ws + 16777216);   // [1024][1024] bf16
  u16*   qkvT     = (u16*)(ws + 25165824);   // [2][3072][2048] bf16
  u16*   xb       = (u16*)(ws + 50331648);   // [4096][1024] bf16 (dead after G1)
  u16*   Hb       = (u16*)(ws + 50331648);   // [2048][2048] bf16 (after xb dead)
  u16*   WaT      = (u16*)(ws + 58720256);   // [3072][1024] bf16 (dead after G1)
  u16*   qkm      = (u16*)(ws + 58720256);   // [4][2048][1024] bf16 (after WaT dead)
  float* hbuf     = (float*)(ws + 75497472);
  float* lat_term = (float*)(ws + 75505664);
  float* out_const= (float*)(ws + 75513856);
  int*   flags    = (int*)(ws + 75522048);
  float* part     = (float*)(ws + 75522304); // [2][16][1024] f32 partial sums

  zero_flags_k<<<1, 64, 0, stream>>>(flags);
  bias_scan_k<<<1024, 256, 0, stream>>>(rel, flags);

  cvt_f2b_k<<<4096, 256, 0, stream>>>(x, xb);                       // x -> bf16
  transpose_f2b_k<<<dim3(48, 16), 256, 0, stream>>>(W_attn, WaT, 1024, 3072);

  GemmOffsets g0; for (int i = 0; i < 4; ++i) { g0.a[i]=0; g0.b[i]=0; g0.c[i]=0; }
  // G1: qkv = x @ W_attn + b_attn   [4096,1024]@[1024,3072]
  gemm_bt_k<1, false><<<dim3(24, 32, 1), 256, 0, stream>>>(
      xb, 1024, WaT, 1024, (void*)qkv, 3072, 1024, b_attn, g0);

  // qkvT[b][c][t] = qkv[b][t][c]
  transpose_b2b_k<<<dim3(48, 32, 2), 256, 0, stream>>>(qkv, qkvT, 2048, 3072);

  conv_h_k<<<2048, 256, 0, stream>>>(alpha, hbuf);
  hb_fill_k<<<16384, 256, 0, stream>>>(hbuf, Hb);

  // G2: qkm[z] = Hb @ (q|k)[b]   z = b*2 + (0:q,1:k); [2048,2048]@[2048,1024]
  GemmOffsets g2;
  for (int i = 0; i < 4; ++i) g2.a[i] = 0;
  g2.b[0] = 0L;            g2.b[1] = 1024L * 2048;
  g2.b[2] = 3072L * 2048;  g2.b[3] = 4096L * 2048;
  g2.c[0] = 0L; g2.c[1] = 2097152L; g2.c[2] = 4194304L; g2.c[3] = 6291456L;
  gemm_bt_k<0, false><<<dim3(8, 16, 4), 256, 0, stream>>>(
      Hb, 2048, qkvT, 2048, (void*)qkm, 1024, 2048, nullptr, g2);

  // latent path (parallel two-stage reduction)
  vmean_part_k<<<dim3(2, 16), 256, 0, stream>>>(qkv, part);
  latent2_k<<<32, 64, 0, stream>>>(part, W_lat, b_lat, W_fuse, b_fuse, lat_term);
  outconst_k<<<dim3(2, 4), 256, 0, stream>>>(lat_term, W_proj, b_proj, out_const);
  wcombT_k<<<4096, 256, 0, stream>>>(W_fuse, W_proj, WcombT);

  // flash attention -> localf [4096][1024]
  fa_k<<<dim3(2, 16, 16), 256, 0, stream>>>(qkm, qkvT, rel, flags, localf);

  // G3: out = localf @ WcombT^T + out_const[b]   [4096,1024]@[1024,1024]
  gemm_bt_k<2, true><<<dim3(8, 32, 1), 256, 0, stream>>>(
      localf, 1024, WcombT, 1024, (void*)out, 1024, 1024, out_const, g0);
}

// Round 4
// 433.000 us; speedup vs baseline: 1.8681x; 1.0909x over previous
//
#include <hip/hip_runtime.h>

typedef unsigned short u16;
typedef __attribute__((ext_vector_type(8))) short bf16x8;
typedef __attribute__((ext_vector_type(4))) float f32x4;
typedef __attribute__((ext_vector_type(4))) unsigned short u16x4;

__device__ __forceinline__ u16 f2b(float f) {
  union { float f; unsigned u; } x; x.f = f;
  unsigned u = x.u;
  return (u16)((u + 0x7fffu + ((u >> 16) & 1u)) >> 16);
}
__device__ __forceinline__ float b2f(u16 b) {
  union { unsigned u; float f; } x; x.u = ((unsigned)b) << 16;
  return x.f;
}

// async global->LDS, 16B per lane; lds base must be wave-uniform.
__device__ __forceinline__ void gload_lds16(const void* g, void* l) {
  __builtin_amdgcn_global_load_lds(
      (const __attribute__((address_space(1))) void*)g,
      (__attribute__((address_space(3))) void*)l, 16, 0, 0);
}

struct GemmOffsets { long a[4]; long b[4]; long c[4]; };

// ---------------- tiny prep kernels ----------------
__global__ void zero_flags_k(int* flags) {
  if (threadIdx.x < 16) flags[threadIdx.x] = 0;
}

// per-head all-zero detection for rel_bias (correct for ANY input)
__global__ void bias_scan_k(const float* __restrict__ rel, int* __restrict__ flags) {
  long base = (long)blockIdx.x * 65536;
  int h = blockIdx.x >> 6;  // 64 blocks per head (head = 2048*2048 floats)
  const float4* p = (const float4*)(rel + base);
  bool nz = false;
  for (int i = threadIdx.x; i < 16384; i += 256) {
    float4 v = p[i];
    nz = nz || (v.x != 0.f) || (v.y != 0.f) || (v.z != 0.f) || (v.w != 0.f);
  }
  if (nz) atomicOr(flags + h, 1);
}

__global__ void cvt_f2b_k(const float* __restrict__ in, u16* __restrict__ out) {
  long i = ((long)blockIdx.x * 256 + threadIdx.x) * 4;
  float4 v = *(const float4*)(in + i);
  u16x4 o;
  o[0] = f2b(v.x); o[1] = f2b(v.y); o[2] = f2b(v.z); o[3] = f2b(v.w);
  *(u16x4*)(out + i) = o;
}

// out[c][r] = in[r][c]; f32 -> bf16. grid (C/64, R/64), 256 thr
__global__ void transpose_f2b_k(const float* __restrict__ in, u16* __restrict__ out,
                                int R, int C) {
  __shared__ float tile[64][68];
  int r0 = blockIdx.y * 64, c0 = blockIdx.x * 64;
  int t = threadIdx.x;
  for (int ch = t; ch < 1024; ch += 256) {
    int r = ch >> 4, q = ch & 15;
    float4 v = *(const float4*)(in + (long)(r0 + r) * C + c0 + q * 4);
    tile[r][q * 4 + 0] = v.x; tile[r][q * 4 + 1] = v.y;
    tile[r][q * 4 + 2] = v.z; tile[r][q * 4 + 3] = v.w;
  }
  __syncthreads();
  for (int ch = t; ch < 1024; ch += 256) {
    int cc = ch >> 4, g = ch & 15;
    u16x4 o;
    o[0] = f2b(tile[g * 4 + 0][cc]); o[1] = f2b(tile[g * 4 + 1][cc]);
    o[2] = f2b(tile[g * 4 + 2][cc]); o[3] = f2b(tile[g * 4 + 3][cc]);
    *(u16x4*)(out + (long)(c0 + cc) * R + r0 + g * 4) = o;
  }
}

// out[z][c][r] = in[z][r][c]; bf16. grid (C/64, R/64, Z), 256 thr
__global__ void transpose_b2b_k(const u16* __restrict__ in, u16* __restrict__ out,
                                int R, int C) {
  __shared__ u16 tile[64][80];
  long zb = (long)blockIdx.z * R * C;
  int r0 = blockIdx.y * 64, c0 = blockIdx.x * 64;
  int t = threadIdx.x;
  for (int ch = t; ch < 512; ch += 256) {
    int r = ch >> 3, q = ch & 7;
    *(bf16x8*)&tile[r][q * 8] =
        *(const bf16x8*)(in + zb + (long)(r0 + r) * C + c0 + q * 8);
  }
  __syncthreads();
  for (int ch = t; ch < 512; ch += 256) {
    int cc = ch >> 3, q = ch & 7;
    bf16x8 v;
#pragma unroll
    for (int k = 0; k < 8; ++k) v[k] = (short)tile[q * 8 + k][cc];
    *(bf16x8*)(out + zb + (long)(c0 + cc) * R + r0 + q * 8) = v;
  }
}

// h = irfft(exp(-j*alpha), n=2048): direct cosine sum with exact integer phase.
__global__ void conv_h_k(const float* __restrict__ alpha, float* __restrict__ hbuf) {
  int tt = blockIdx.x;   // 0..2047
  int t = threadIdx.x;   // 256
  float a = alpha[0];
  const float wph = 3.14159265358979323846f / 1024.f;
  float acc = 0.f;
  for (int j = 1 + t; j < 1024; j += 256) {
    int ph = (j * tt) & 2047;
    acc += 2.f * __expf(-a * (float)j) * __cosf((float)ph * wph);
  }
  if (t == 0) {
    acc += 1.0f;  // j = 0 term
    int ph = (1024 * tt) & 2047;
    acc += __expf(-a * 1024.f) * __cosf((float)ph * wph);
  }
  __shared__ float red[256];
  red[t] = acc;
  __syncthreads();
  for (int s = 128; s > 0; s >>= 1) {
    if (t < s) red[t] += red[t + s];
    __syncthreads();
  }
  if (t == 0) hbuf[tt] = red[0] * (1.f / 2048.f);
}

__global__ void hb_fill_k(const float* __restrict__ hbuf, u16* __restrict__ Hb) {
  long idx = (long)blockIdx.x * 256 + threadIdx.x;  // < 2048*2048
  int tt = (int)(idx >> 11), u = (int)(idx & 2047);
  Hb[idx] = f2b(hbuf[(tt - u) & 2047]);
}

// ---------------- shared bf16 MFMA GEMM: C = A[M,K] @ Bt[N,K]^T ----------------
// m97 structure: 128x128 tile, BK=64, 4 waves, global_load_lds staging with
// linear LDS dest + inverse-swizzled global source; swizzled ds_read side.
// BIAS_MODE: 0 none, 1 bias[col], 2 bias[(row>>11)*ldc+col]
template<int BIAS_MODE, bool OUT_F32>
__global__ __launch_bounds__(256)
void gemm_bt_k(const u16* __restrict__ A, int lda,
               const u16* __restrict__ Bt, int ldb,
               void* __restrict__ Cv, int ldc, int K,
               const float* __restrict__ bias, GemmOffsets offs) {
  __shared__ u16 As[128 * 64];
  __shared__ u16 Bs[128 * 64];
  const int z = blockIdx.z;
  const u16* Ab = A + offs.a[z];
  const u16* Bb = Bt + offs.b[z];
  const int m0 = blockIdx.y * 128, n0 = blockIdx.x * 128;
  const int t = threadIdx.x;
  const int w = t >> 6, l = t & 63;
  const int wr = (w >> 1) * 64, wc = (w & 1) * 64;
  const int lrow = l & 15, lk = l >> 4;

  f32x4 acc[4][4] = {};

  for (int k0 = 0; k0 < K; k0 += 64) {
    __syncthreads();
#pragma unroll
    for (int q = 0; q < 4; ++q) {
      int ch = (w * 4 + q) * 64 + l;       // linear 16B-chunk index
      int row = ch >> 3;
      int cg = (ch & 7) ^ (row & 7);       // inverse-swizzled source column
      gload_lds16(Ab + (long)(m0 + row) * lda + k0 + cg * 8, &As[(w * 4 + q) * 512]);
      gload_lds16(Bb + (long)(n0 + row) * ldb + k0 + cg * 8, &Bs[(w * 4 + q) * 512]);
    }
    __syncthreads();
#pragma unroll
    for (int kk = 0; kk < 2; ++kk) {
      bf16x8 af[4], bfr[4];
#pragma unroll
      for (int i = 0; i < 4; ++i) {
        int ar = wr + i * 16 + lrow;
        af[i] = *(const bf16x8*)&As[ar * 64 + ((((kk << 2) | lk) ^ (ar & 7)) << 3)];
        int br = wc + i * 16 + lrow;
        bfr[i] = *(const bf16x8*)&Bs[br * 64 + ((((kk << 2) | lk) ^ (br & 7)) << 3)];
      }
#pragma unroll
      for (int i = 0; i < 4; ++i)
#pragma unroll
        for (int j = 0; j < 4; ++j)
          acc[i][j] = __builtin_amdgcn_mfma_f32_16x16x32_bf16(af[i], bfr[j], acc[i][j], 0, 0, 0);
    }
  }

  const long coff = offs.c[z];
#pragma unroll
  for (int i = 0; i < 4; ++i)
#pragma unroll
    for (int j = 0; j < 4; ++j)
#pragma unroll
      for (int r = 0; r < 4; ++r) {
        int row = m0 + wr + i * 16 + lk * 4 + r;
        int col = n0 + wc + j * 16 + lrow;
        float v = acc[i][j][r];
        if (BIAS_MODE == 1) v += bias[col];
        if (BIAS_MODE == 2) v += bias[(row >> 11) * ldc + col];
        if (OUT_F32)
          ((float*)Cv)[coff + (long)row * ldc + col] = v;
        else
          ((u16*)Cv)[coff + (long)row * ldc + col] = f2b(v);
      }
}

// ---------------- flash attention v3 ----------------
// grid (B, H, T/128); 256 thr, 4 waves; each wave owns 32 Q rows.
// No-max softmax (clamped exp2), deferred sum reduction, padded per-wave P
// tile, double-buffered K/V staged via global_load_lds (prefetch after QK^T).
__global__ __launch_bounds__(256)
void fa_k(const u16* __restrict__ qkm, const u16* __restrict__ qkvT,
          const float* __restrict__ rel, const int* __restrict__ flags,
          u16* __restrict__ localf) {
  const int b = blockIdx.x, h = blockIdx.y;
  const int t0 = blockIdx.z * 128;
  const int t = threadIdx.x, w = t >> 6, l = t & 63;
  const int lrow = l & 15, lk = l >> 4;
  __shared__ u16 QPs[9216];      // Q staging (8192 u16), then per-wave P [32][72]
  __shared__ u16 Ks[2][64 * 64];
  __shared__ u16 Vs[2][64 * 64];

  const bool has_bias = (flags[h] != 0);
  const u16* qm = qkm + (long)(b * 2) * (2048 * 1024);
  const u16* km = qkm + (long)(b * 2 + 1) * (2048 * 1024);

  // stage Q tile: linear LDS + inverse-swizzled source
#pragma unroll
  for (int q = 0; q < 4; ++q) {
    int ch = (w * 4 + q) * 64 + l;
    int r = ch >> 3;
    int cg = (ch & 7) ^ (r & 7);
    gload_lds16(qm + (long)(t0 + r) * 1024 + h * 64 + cg * 8, &QPs[(w * 4 + q) * 512]);
  }
  // K/V tile staging (double-buffered)
  auto stage = [&](int tile, int buf) {
    int s0 = tile * 64;
#pragma unroll
    for (int q = 0; q < 2; ++q) {
      int ch = (w * 2 + q) * 64 + l;
      int r = ch >> 3;
      int cg = (ch & 7) ^ (r & 7);
      gload_lds16(km + (long)(s0 + r) * 1024 + h * 64 + cg * 8,
                  &Ks[buf][(w * 2 + q) * 512]);
      gload_lds16(qkvT + ((long)b * 3072 + 2048 + h * 64 + r) * 2048 + s0 + cg * 8,
                  &Vs[buf][(w * 2 + q) * 512]);
    }
  };
  stage(0, 0);
  __syncthreads();

  bf16x8 qf[2][2];
#pragma unroll
  for (int i = 0; i < 2; ++i)
#pragma unroll
    for (int kk = 0; kk < 2; ++kk) {
      int r = w * 32 + i * 16 + lrow;
      qf[i][kk] = *(const bf16x8*)&QPs[r * 64 + ((((kk << 2) | lk) ^ (r & 7)) << 3)];
    }
  __syncthreads();  // all waves done reading Q before any P store into QPs

  // per-wave padded P tile: rows stride 72 u16 (144 B, 16B-aligned rows)
  u16* Pw = QPs + w * 2304 + (lk * 4) * 72 + lrow;       // write base (+i*1152+r*72+j*16)
  const u16* Pr = QPs + w * 2304 + lrow * 72 + lk * 8;   // read base  (+i*1152+kk*32)

  f32x4 o[2][4] = {};
  float lsum[2][4] = {};

  for (int it = 0; it < 32; ++it) {
    const int cur = it & 1;
    const u16* Kb = Ks[cur];
    const u16* Vb = Vs[cur];

    // QK^T
    f32x4 sa[2][4] = {};
#pragma unroll
    for (int kk = 0; kk < 2; ++kk) {
      bf16x8 kf[4];
#pragma unroll
      for (int j = 0; j < 4; ++j) {
        int r = j * 16 + lrow;
        kf[j] = *(const bf16x8*)&Kb[r * 64 + ((((kk << 2) | lk) ^ (r & 7)) << 3)];
      }
#pragma unroll
      for (int i = 0; i < 2; ++i)
#pragma unroll
        for (int j = 0; j < 4; ++j)
          sa[i][j] = __builtin_amdgcn_mfma_f32_16x16x32_bf16(qf[i][kk], kf[j], sa[i][j], 0, 0, 0);
    }

    // prefetch next K/V tile (in flight during softmax + PV; drains at barrier)
    if (it < 31) stage(it + 1, cur ^ 1);

    // softmax-lite: p = exp2((S/8 + bias) * log2e), clamped; no max tracking
#pragma unroll
    for (int i = 0; i < 2; ++i)
#pragma unroll
      for (int j = 0; j < 4; ++j)
#pragma unroll
        for (int r = 0; r < 4; ++r) {
          float vv = sa[i][j][r] * 0.1803368867f;  // 0.125 * log2(e)
          if (has_bias)
            vv += 1.4426950409f *
                  rel[((long)h * 2048 + t0 + w * 32 + i * 16 + lk * 4 + r) * 2048
                      + it * 64 + j * 16 + lrow];
          float p = exp2f(fminf(vv, 86.0f));
          lsum[i][r] += p;
          Pw[i * 1152 + r * 72 + j * 16] = f2b(p);
        }

    // PV
#pragma unroll
    for (int kk = 0; kk < 2; ++kk) {
      bf16x8 pf[2], vf[4];
#pragma unroll
      for (int i = 0; i < 2; ++i)
        pf[i] = *(const bf16x8*)&Pr[i * 1152 + kk * 32];
#pragma unroll
      for (int j = 0; j < 4; ++j) {
        int r = j * 16 + lrow;
        vf[j] = *(const bf16x8*)&Vb[r * 64 + ((((kk << 2) | lk) ^ (r & 7)) << 3)];
      }
#pragma unroll
      for (int i = 0; i < 2; ++i)
#pragma unroll
        for (int j = 0; j < 4; ++j)
          o[i][j] = __builtin_amdgcn_mfma_f32_16x16x32_bf16(pf[i], vf[j], o[i][j], 0, 0, 0);
    }
    __syncthreads();  // staging drained + all readers of cur done
  }

  // deferred denominator: reduce over the 16-lane key dimension, once
#pragma unroll
  for (int i = 0; i < 2; ++i)
#pragma unroll
    for (int r = 0; r < 4; ++r) {
      float s = lsum[i][r];
      s += __shfl_xor(s, 1);
      s += __shfl_xor(s, 2);
      s += __shfl_xor(s, 4);
      s += __shfl_xor(s, 8);
      float inv = 1.0f / s;
#pragma unroll
      for (int j = 0; j < 4; ++j)
        localf[((long)b * 2048 + t0 + w * 32 + i * 16 + lk * 4 + r) * 1024
               + h * 64 + j * 16 + lrow] = f2b(o[i][j][r] * inv);
    }
}

// ---------------- latent path: two-stage deterministic reduction ----------------
__global__ void vmean_part_k(const u16* __restrict__ qkv, float* __restrict__ part) {
  int b = blockIdx.x, ch = blockIdx.y;
  int t = threadIdx.x;
  int c0 = (t & 127) * 8;
  int rh = t >> 7;
  float acc[8] = {};
  for (int r = rh; r < 128; r += 2) {
    bf16x8 v = *(const bf16x8*)(qkv + ((long)b * 2048 + ch * 128 + r) * 3072 + 2048 + c0);
#pragma unroll
    for (int k = 0; k < 8; ++k) acc[k] += b2f((u16)(unsigned short)v[k]);
  }
  __shared__ float red[1024];
  if (rh == 1) {
#pragma unroll
    for (int k = 0; k < 8; ++k) red[c0 + k] = acc[k];
  }
  __syncthreads();
  if (rh == 0) {
#pragma unroll
    for (int k = 0; k < 8; ++k)
      part[((long)b * 16 + ch) * 1024 + c0 + k] = acc[k] + red[c0 + k];
  }
}

__global__ void latent2_k(const float* __restrict__ part, const float* __restrict__ W_lat,
                          const float* __restrict__ b_lat, const float* __restrict__ W_fuse,
                          const float* __restrict__ b_fuse, float* __restrict__ lat_term) {
  int bh = blockIdx.x, b = bh >> 4, h = bh & 15;
  int d = threadIdx.x;  // 64 threads
  float s = 0.f;
#pragma unroll
  for (int c = 0; c < 16; ++c) s += part[((long)b * 16 + c) * 1024 + h * 64 + d];
  __shared__ float mv[64], lat[64];
  mv[d] = s * (1.f / 2048.f);
  __syncthreads();
  float acc = b_lat[d];
  for (int k = 0; k < 64; ++k) acc += mv[k] * W_lat[k * 64 + d];
  lat[d] = acc;
  __syncthreads();
  float acc2 = b_fuse[d];
  for (int k = 0; k < 64; ++k) acc2 += lat[k] * W_fuse[(64 + k) * 64 + d];
  lat_term[bh * 64 + d] = acc2;
}

__global__ void outconst_k(const float* __restrict__ lat_term, const float* __restrict__ W_proj,
                           const float* __restrict__ b_proj, float* __restrict__ out_const) {
  int b = blockIdx.x;
  int c = blockIdx.y * 256 + threadIdx.x;
  float acc = b_proj[c];
  for (int hd = 0; hd < 1024; ++hd)
    acc += lat_term[b * 1024 + hd] * W_proj[(long)hd * 1024 + c];
  out_const[b * 1024 + c] = acc;
}

// WcombT[c][h*64+d0] = sum_d1 W_fuse[d0][d1] * W_proj[h*64+d1][c]
__global__ void wcombT_k(const float* __restrict__ W_fuse, const float* __restrict__ W_proj,
                         u16* __restrict__ WcombT) {
  long idx = (long)blockIdx.x * 256 + threadIdx.x;  // 1048576
  int c = (int)(idx >> 10), hd0 = (int)(idx & 1023);
  int h = hd0 >> 6, d0 = hd0 & 63;
  float acc = 0.f;
  for (int d1 = 0; d1 < 64; ++d1)
    acc += W_fuse[d0 * 64 + d1] * W_proj[(long)(h * 64 + d1) * 1024 + c];
  WcombT[(long)c * 1024 + hd0] = f2b(acc);
}

// ---------------- launch ----------------
extern "C" void kernel_launch(void* const* d_in, const int* in_sizes, int n_in,
                              void* d_out, int out_size, void* d_ws, size_t ws_size,
                              hipStream_t stream) {
  (void)in_sizes; (void)n_in; (void)out_size; (void)ws_size;
  const float* x      = (const float*)d_in[0];
  const float* W_attn = (const float*)d_in[1];
  const float* b_attn = (const float*)d_in[2];
  const float* W_proj = (const float*)d_in[3];
  const float* b_proj = (const float*)d_in[4];
  const float* rel    = (const float*)d_in[5];
  const float* alpha  = (const float*)d_in[6];
  const float* W_lat  = (const float*)d_in[7];
  const float* b_lat  = (const float*)d_in[8];
  const float* W_fuse = (const float*)d_in[9];
  const float* b_fuse = (const float*)d_in[10];
  float* out = (float*)d_out;
  char* ws = (char*)d_ws;

  // workspace layout (bytes); lifetime-safe reuse
  u16*   qkv      = (u16*)(ws + 0);          // [4096][3072] bf16 (dead after vmean_part_k)
  u16*   localf   = (u16*)(ws + 0);          // [4096][1024] bf16 (written by fa_k)
  u16*   WcombT   = (u16*)(ws + 16777216);   // [1024][1024] bf16
  u16*   qkvT     = (u16*)(ws + 25165824);   // [2][3072][2048] bf16
  u16*   xb       = (u16*)(ws + 50331648);   // [4096][1024] bf16 (dead after G1)
  u16*   Hb       = (u16*)(ws + 50331648);   // [2048][2048] bf16 (after xb dead)
  u16*   WaT      = (u16*)(ws + 58720256);   // [3072][1024] bf16 (dead after G1)
  u16*   qkm      = (u16*)(ws + 58720256);   // [4][2048][1024] bf16 (after WaT dead)
  float* hbuf     = (float*)(ws + 75497472);
  float* lat_term = (float*)(ws + 75505664);
  float* out_const= (float*)(ws + 75513856);
  int*   flags    = (int*)(ws + 75522048);
  float* part     = (float*)(ws + 75522304); // [2][16][1024] f32 partial sums

  zero_flags_k<<<1, 64, 0, stream>>>(flags);
  bias_scan_k<<<1024, 256, 0, stream>>>(rel, flags);

  cvt_f2b_k<<<4096, 256, 0, stream>>>(x, xb);                       // x -> bf16
  transpose_f2b_k<<<dim3(48, 16), 256, 0, stream>>>(W_attn, WaT, 1024, 3072);

  GemmOffsets g0; for (int i = 0; i < 4; ++i) { g0.a[i]=0; g0.b[i]=0; g0.c[i]=0; }
  // G1: qkv = x @ W_attn + b_attn   [4096,1024]@[1024,3072]
  gemm_bt_k<1, false><<<dim3(24, 32, 1), 256, 0, stream>>>(
      xb, 1024, WaT, 1024, (void*)qkv, 3072, 1024, b_attn, g0);

  // qkvT[b][c][t] = qkv[b][t][c]
  transpose_b2b_k<<<dim3(48, 32, 2), 256, 0, stream>>>(qkv, qkvT, 2048, 3072);

  conv_h_k<<<2048, 256, 0, stream>>>(alpha, hbuf);
  hb_fill_k<<<16384, 256, 0, stream>>>(hbuf, Hb);

  // G2: qkm[z] = Hb @ (q|k)[b]   z = b*2 + (0:q,1:k); [2048,2048]@[2048,1024]
  GemmOffsets g2;
  for (int i = 0; i < 4; ++i) g2.a[i] = 0;
  g2.b[0] = 0L;            g2.b[1] = 1024L * 2048;
  g2.b[2] = 3072L * 2048;  g2.b[3] = 4096L * 2048;
  g2.c[0] = 0L; g2.c[1] = 2097152L; g2.c[2] = 4194304L; g2.c[3] = 6291456L;
  gemm_bt_k<0, false><<<dim3(8, 16, 4), 256, 0, stream>>>(
      Hb, 2048, qkvT, 2048, (void*)qkm, 1024, 2048, nullptr, g2);

  // latent path (parallel two-stage reduction)
  vmean_part_k<<<dim3(2, 16), 256, 0, stream>>>(qkv, part);
  latent2_k<<<32, 64, 0, stream>>>(part, W_lat, b_lat, W_fuse, b_fuse, lat_term);
  outconst_k<<<dim3(2, 4), 256, 0, stream>>>(lat_term, W_proj, b_proj, out_const);
  wcombT_k<<<4096, 256, 0, stream>>>(W_fuse, W_proj, WcombT);

  // flash attention -> localf [4096][1024]
  fa_k<<<dim3(2, 16, 16), 256, 0, stream>>>(qkm, qkvT, rel, flags, localf);

  // G3: out = localf @ WcombT^T + out_const[b]   [4096,1024]@[1024,1024]
  gemm_bt_k<2, true><<<dim3(8, 32, 1), 256, 0, stream>>>(
      localf, 1024, WcombT, 1024, (void*)out, 1024, 1024, out_const, g0);
}

// Round 5
// 424.953 us; speedup vs baseline: 1.9035x; 1.0189x over previous
//
#include <hip/hip_runtime.h>

typedef unsigned short u16;
typedef __attribute__((ext_vector_type(8))) short bf16x8;
typedef __attribute__((ext_vector_type(4))) float f32x4;
typedef __attribute__((ext_vector_type(4))) unsigned short u16x4;

__device__ __forceinline__ u16 f2b(float f) {
  union { float f; unsigned u; } x; x.f = f;
  unsigned u = x.u;
  return (u16)((u + 0x7fffu + ((u >> 16) & 1u)) >> 16);
}
__device__ __forceinline__ float b2f(u16 b) {
  union { unsigned u; float f; } x; x.u = ((unsigned)b) << 16;
  return x.f;
}

// async global->LDS, 16B per lane; lds base must be wave-uniform.
__device__ __forceinline__ void gload_lds16(const void* g, void* l) {
  __builtin_amdgcn_global_load_lds(
      (const __attribute__((address_space(1))) void*)g,
      (__attribute__((address_space(3))) void*)l, 16, 0, 0);
}

struct GemmOffsets { long a[4]; long b[4]; long c[4]; };

// ---------------- fused prep: everything that depends only on inputs ----------------
// blocks [0,4096): x -> xb (bf16);  [4096,4864): W_attn -> WaT;  [4864,5888): x -> xT;
// [5888,9984): WcombT;  [9984,12032): conv_h (h filter).  Block 0 also zeroes flags.
__device__ __forceinline__ void tr_f2b_body(const float* __restrict__ in,
                                            u16* __restrict__ out, int R, int C,
                                            int bx, int by, int t, float* tile) {
  int r0 = by * 64, c0 = bx * 64;
  for (int ch = t; ch < 1024; ch += 256) {
    int r = ch >> 4, q = ch & 15;
    float4 v = *(const float4*)(in + (long)(r0 + r) * C + c0 + q * 4);
    tile[r * 68 + q * 4 + 0] = v.x; tile[r * 68 + q * 4 + 1] = v.y;
    tile[r * 68 + q * 4 + 2] = v.z; tile[r * 68 + q * 4 + 3] = v.w;
  }
  __syncthreads();
  for (int ch = t; ch < 1024; ch += 256) {
    int cc = ch >> 4, g = ch & 15;
    u16x4 o;
    o[0] = f2b(tile[(g * 4 + 0) * 68 + cc]); o[1] = f2b(tile[(g * 4 + 1) * 68 + cc]);
    o[2] = f2b(tile[(g * 4 + 2) * 68 + cc]); o[3] = f2b(tile[(g * 4 + 3) * 68 + cc]);
    *(u16x4*)(out + (long)(c0 + cc) * R + r0 + g * 4) = o;
  }
}

__global__ void prep_k(const float* __restrict__ x, const float* __restrict__ W_attn,
                       const float* __restrict__ W_fuse, const float* __restrict__ W_proj,
                       const float* __restrict__ alpha,
                       u16* __restrict__ xb, u16* __restrict__ WaT, u16* __restrict__ xT,
                       u16* __restrict__ WcombT, float* __restrict__ hbuf,
                       int* __restrict__ flags) {
  __shared__ float smem[64 * 68];
  const int id = blockIdx.x, t = threadIdx.x;
  if (id == 0 && t < 16) flags[t] = 0;
  if (id < 4096) {                       // x -> xb bf16
    long i = ((long)id * 256 + t) * 4;
    float4 v = *(const float4*)(x + i);
    u16x4 o;
    o[0] = f2b(v.x); o[1] = f2b(v.y); o[2] = f2b(v.z); o[3] = f2b(v.w);
    *(u16x4*)(xb + i) = o;
  } else if (id < 4864) {                // W_attn[1024][3072] -> WaT[3072][1024]
    int local = id - 4096;
    tr_f2b_body(W_attn, WaT, 1024, 3072, local % 48, local / 48, t, smem);
  } else if (id < 5888) {                // x[z][2048][1024] -> xT[z][1024][2048]
    int local = id - 4864;
    int bx = local & 15, by = (local >> 4) & 31, z = local >> 9;
    tr_f2b_body(x + (long)z * 2048 * 1024, xT + (long)z * 1024 * 2048,
                2048, 1024, bx, by, t, smem);
  } else if (id < 9984) {                // WcombT[c][h*64+d0] = sum_d1 Wf[d0][d1] Wp[h*64+d1][c]
    long idx = (long)(id - 5888) * 256 + t;
    int c = (int)(idx >> 10), hd0 = (int)(idx & 1023);
    int h = hd0 >> 6, d0 = hd0 & 63;
    float acc = 0.f;
    for (int d1 = 0; d1 < 64; ++d1)
      acc += W_fuse[d0 * 64 + d1] * W_proj[(long)(h * 64 + d1) * 1024 + c];
    WcombT[(long)c * 1024 + hd0] = f2b(acc);
  } else {                               // conv_h: h = irfft(exp(-j*alpha), n=2048)
    int tt = id - 9984;
    float a = alpha[0];
    const float wph = 3.14159265358979323846f / 1024.f;
    float acc = 0.f;
    for (int j = 1 + t; j < 1024; j += 256) {
      int ph = (j * tt) & 2047;
      acc += 2.f * __expf(-a * (float)j) * __cosf((float)ph * wph);
    }
    if (t == 0) {
      acc += 1.0f;
      int ph = (1024 * tt) & 2047;
      acc += __expf(-a * 1024.f) * __cosf((float)ph * wph);
    }
    float* red = smem;
    red[t] = acc;
    __syncthreads();
    for (int s = 128; s > 0; s >>= 1) {
      if (t < s) red[t] += red[t + s];
      __syncthreads();
    }
    if (t == 0) hbuf[tt] = red[0] * (1.f / 2048.f);
  }
}

// ---------------- bias scan + Hb fill (both depend only on prep) ----------------
__global__ void scanhb_k(const float* __restrict__ rel, int* __restrict__ flags,
                         const float* __restrict__ hbuf, u16* __restrict__ Hb) {
  const int id = blockIdx.x, t = threadIdx.x;
  if (id < 1024) {                       // per-head all-zero detection of rel_bias
    long base = (long)id * 65536;
    int h = id >> 6;
    const float4* p = (const float4*)(rel + base);
    bool nz = false;
    for (int i = t; i < 16384; i += 256) {
      float4 v = p[i];
      nz = nz || (v.x != 0.f) || (v.y != 0.f) || (v.z != 0.f) || (v.w != 0.f);
    }
    if (nz) atomicOr(flags + h, 1);
  } else {                               // Hb[tt][u] = h[(tt-u) & 2047]
    long idx = (long)(id - 1024) * 256 + t;
    int tt = (int)(idx >> 11), u = (int)(idx & 2047);
    Hb[idx] = f2b(hbuf[(tt - u) & 2047]);
  }
}

// ---------------- shared bf16 MFMA GEMM: C = A[M,K] @ Bt[N,K]^T ----------------
// m97 structure: 128x128 tile, BK=64, 4 waves, global_load_lds staging with
// linear LDS dest + inverse-swizzled global source; swizzled ds_read side.
// BIAS_MODE: 0 none, 1 bias[col], 2 bias[(row>>11)*ldc+col]
template<int BIAS_MODE, bool OUT_F32>
__global__ __launch_bounds__(256)
void gemm_bt_k(const u16* __restrict__ A, int lda,
               const u16* __restrict__ Bt, int ldb,
               void* __restrict__ Cv, int ldc, int K,
               const float* __restrict__ bias, GemmOffsets offs) {
  __shared__ u16 As[128 * 64];
  __shared__ u16 Bs[128 * 64];
  const int z = blockIdx.z;
  const u16* Ab = A + offs.a[z];
  const u16* Bb = Bt + offs.b[z];
  const int m0 = blockIdx.y * 128, n0 = blockIdx.x * 128;
  const int t = threadIdx.x;
  const int w = t >> 6, l = t & 63;
  const int wr = (w >> 1) * 64, wc = (w & 1) * 64;
  const int lrow = l & 15, lk = l >> 4;

  f32x4 acc[4][4] = {};

  for (int k0 = 0; k0 < K; k0 += 64) {
    __syncthreads();
#pragma unroll
    for (int q = 0; q < 4; ++q) {
      int ch = (w * 4 + q) * 64 + l;       // linear 16B-chunk index
      int row = ch >> 3;
      int cg = (ch & 7) ^ (row & 7);       // inverse-swizzled source column
      gload_lds16(Ab + (long)(m0 + row) * lda + k0 + cg * 8, &As[(w * 4 + q) * 512]);
      gload_lds16(Bb + (long)(n0 + row) * ldb + k0 + cg * 8, &Bs[(w * 4 + q) * 512]);
    }
    __syncthreads();
#pragma unroll
    for (int kk = 0; kk < 2; ++kk) {
      bf16x8 af[4], bfr[4];
#pragma unroll
      for (int i = 0; i < 4; ++i) {
        int ar = wr + i * 16 + lrow;
        af[i] = *(const bf16x8*)&As[ar * 64 + ((((kk << 2) | lk) ^ (ar & 7)) << 3)];
        int br = wc + i * 16 + lrow;
        bfr[i] = *(const bf16x8*)&Bs[br * 64 + ((((kk << 2) | lk) ^ (br & 7)) << 3)];
      }
#pragma unroll
      for (int i = 0; i < 4; ++i)
#pragma unroll
        for (int j = 0; j < 4; ++j)
          acc[i][j] = __builtin_amdgcn_mfma_f32_16x16x32_bf16(af[i], bfr[j], acc[i][j], 0, 0, 0);
    }
  }

  const long coff = offs.c[z];
#pragma unroll
  for (int i = 0; i < 4; ++i)
#pragma unroll
    for (int j = 0; j < 4; ++j)
#pragma unroll
      for (int r = 0; r < 4; ++r) {
        int row = m0 + wr + i * 16 + lk * 4 + r;
        int col = n0 + wc + j * 16 + lrow;
        float v = acc[i][j][r];
        if (BIAS_MODE == 1) v += bias[col];
        if (BIAS_MODE == 2) v += bias[(row >> 11) * ldc + col];
        if (OUT_F32)
          ((float*)Cv)[coff + (long)row * ldc + col] = v;
        else
          ((u16*)Cv)[coff + (long)row * ldc + col] = f2b(v);
      }
}

// ---------------- V transpose + v-mean partials (both consume v) ----------------
__global__ void tVvm_k(const u16* __restrict__ v, u16* __restrict__ vT,
                       float* __restrict__ part) {
  __shared__ u16 tile[64 * 80];
  __shared__ float red[1024];
  const int id = blockIdx.x, t = threadIdx.x;
  if (id < 1024) {                       // v[z][2048][1024] -> vT[z][1024][2048]
    int bx = id & 15, by = (id >> 4) & 31, z = id >> 9;
    long zb = (long)z * 2048 * 1024;
    int r0 = by * 64, c0 = bx * 64;
    for (int ch = t; ch < 512; ch += 256) {
      int r = ch >> 3, q = ch & 7;
      *(bf16x8*)&tile[r * 80 + q * 8] =
          *(const bf16x8*)(v + zb + (long)(r0 + r) * 1024 + c0 + q * 8);
    }
    __syncthreads();
    for (int ch = t; ch < 512; ch += 256) {
      int cc = ch >> 3, q = ch & 7;
      bf16x8 o;
#pragma unroll
      for (int k = 0; k < 8; ++k) o[k] = (short)tile[(q * 8 + k) * 80 + cc];
      *(bf16x8*)(vT + zb + (long)(c0 + cc) * 2048 + r0 + q * 8) = o;
    }
  } else {                               // partial column sums of v
    int ch2 = id - 1024;
    int b = ch2 >> 4, chk = ch2 & 15;
    int c0 = (t & 127) * 8;
    int rh = t >> 7;
    float acc[8] = {};
    for (int r = rh; r < 128; r += 2) {
      bf16x8 vv = *(const bf16x8*)(v + ((long)b * 2048 + chk * 128 + r) * 1024 + c0);
#pragma unroll
      for (int k = 0; k < 8; ++k) acc[k] += b2f((u16)(unsigned short)vv[k]);
    }
    if (rh == 1) {
#pragma unroll
      for (int k = 0; k < 8; ++k) red[c0 + k] = acc[k];
    }
    __syncthreads();
    if (rh == 0) {
#pragma unroll
      for (int k = 0; k < 8; ++k)
        part[((long)b * 16 + chk) * 1024 + c0 + k] = acc[k] + red[c0 + k];
    }
  }
}

// ---------------- latent chain: mean->W_lat->W_fuse[64:]->W_proj const ----------------
// grid (B), 1024 threads.
__global__ void latent_k(const float* __restrict__ part, const float* __restrict__ W_lat,
                         const float* __restrict__ b_lat, const float* __restrict__ W_fuse,
                         const float* __restrict__ b_fuse, const float* __restrict__ W_proj,
                         const float* __restrict__ b_proj, float* __restrict__ out_const) {
  const int b = blockIdx.x, t = threadIdx.x;
  const int h = t >> 6, d = t & 63;
  __shared__ float mv[1024], lat[1024];
  float s = 0.f;
#pragma unroll
  for (int c = 0; c < 16; ++c) s += part[((long)b * 16 + c) * 1024 + t];
  mv[t] = s * (1.f / 2048.f);
  __syncthreads();
  float acc = b_lat[d];
  for (int k = 0; k < 64; ++k) acc += mv[h * 64 + k] * W_lat[k * 64 + d];
  lat[t] = acc;
  __syncthreads();
  float acc2 = b_fuse[d];
  for (int k = 0; k < 64; ++k) acc2 += lat[h * 64 + k] * W_fuse[(64 + k) * 64 + d];
  __syncthreads();
  mv[t] = acc2;                           // lat_term
  __syncthreads();
  float acc3 = b_proj[t];
  for (int hd = 0; hd < 1024; ++hd) acc3 += mv[hd] * W_proj[(long)hd * 1024 + t];
  out_const[b * 1024 + t] = acc3;
}

// ---------------- flash attention ----------------
// grid (B, H, T/128); 256 thr, 4 waves; each wave owns 32 Q rows.
// qkm2 layout [b][t][{q:0..1023, k:1024..2047}], row stride 2048.
// vT layout [b][ch][t], row stride 2048.
__global__ __launch_bounds__(256)
void fa_k(const u16* __restrict__ qkm2, const u16* __restrict__ vT,
          const float* __restrict__ rel, const int* __restrict__ flags,
          u16* __restrict__ localf) {
  const int b = blockIdx.x, h = blockIdx.y;
  const int t0 = blockIdx.z * 128;
  const int t = threadIdx.x, w = t >> 6, l = t & 63;
  const int lrow = l & 15, lk = l >> 4;
  __shared__ u16 QPs[9216];      // Q staging (8192 u16), then per-wave P [32][72]
  __shared__ u16 Ks[2][64 * 64];
  __shared__ u16 Vs[2][64 * 64];

  const bool has_bias = (flags[h] != 0);
  const u16* qm = qkm2 + (long)b * 2048 * 2048;
  const u16* km = qm + 1024;

  // stage Q tile: linear LDS + inverse-swizzled source
#pragma unroll
  for (int q = 0; q < 4; ++q) {
    int ch = (w * 4 + q) * 64 + l;
    int r = ch >> 3;
    int cg = (ch & 7) ^ (r & 7);
    gload_lds16(qm + (long)(t0 + r) * 2048 + h * 64 + cg * 8, &QPs[(w * 4 + q) * 512]);
  }
  // K/V tile staging (double-buffered)
  auto stage = [&](int tile, int buf) {
    int s0 = tile * 64;
#pragma unroll
    for (int q = 0; q < 2; ++q) {
      int ch = (w * 2 + q) * 64 + l;
      int r = ch >> 3;
      int cg = (ch & 7) ^ (r & 7);
      gload_lds16(km + (long)(s0 + r) * 2048 + h * 64 + cg * 8,
                  &Ks[buf][(w * 2 + q) * 512]);
      gload_lds16(vT + ((long)b * 1024 + h * 64 + r) * 2048 + s0 + cg * 8,
                  &Vs[buf][(w * 2 + q) * 512]);
    }
  };
  stage(0, 0);
  __syncthreads();

  bf16x8 qf[2][2];
#pragma unroll
  for (int i = 0; i < 2; ++i)
#pragma unroll
    for (int kk = 0; kk < 2; ++kk) {
      int r = w * 32 + i * 16 + lrow;
      qf[i][kk] = *(const bf16x8*)&QPs[r * 64 + ((((kk << 2) | lk) ^ (r & 7)) << 3)];
    }
  __syncthreads();  // all waves done reading Q before any P store into QPs

  // per-wave padded P tile: rows stride 72 u16 (144 B, 16B-aligned rows)
  u16* Pw = QPs + w * 2304 + (lk * 4) * 72 + lrow;       // write base (+i*1152+r*72+j*16)
  const u16* Pr = QPs + w * 2304 + lrow * 72 + lk * 8;   // read base  (+i*1152+kk*32)

  f32x4 o[2][4] = {};
  float lsum[2][4] = {};

  for (int it = 0; it < 32; ++it) {
    const int cur = it & 1;
    const u16* Kb = Ks[cur];
    const u16* Vb = Vs[cur];

    // QK^T
    f32x4 sa[2][4] = {};
#pragma unroll
    for (int kk = 0; kk < 2; ++kk) {
      bf16x8 kf[4];
#pragma unroll
      for (int j = 0; j < 4; ++j) {
        int r = j * 16 + lrow;
        kf[j] = *(const bf16x8*)&Kb[r * 64 + ((((kk << 2) | lk) ^ (r & 7)) << 3)];
      }
#pragma unroll
      for (int i = 0; i < 2; ++i)
#pragma unroll
        for (int j = 0; j < 4; ++j)
          sa[i][j] = __builtin_amdgcn_mfma_f32_16x16x32_bf16(qf[i][kk], kf[j], sa[i][j], 0, 0, 0);
    }

    // prefetch next K/V tile (in flight during softmax + PV; drains at barrier)
    if (it < 31) stage(it + 1, cur ^ 1);

    // softmax-lite: p = exp2((S/8 + bias) * log2e), clamped; no max tracking
#pragma unroll
    for (int i = 0; i < 2; ++i)
#pragma unroll
      for (int j = 0; j < 4; ++j)
#pragma unroll
        for (int r = 0; r < 4; ++r) {
          float vv = sa[i][j][r] * 0.1803368867f;  // 0.125 * log2(e)
          if (has_bias)
            vv += 1.4426950409f *
                  rel[((long)h * 2048 + t0 + w * 32 + i * 16 + lk * 4 + r) * 2048
                      + it * 64 + j * 16 + lrow];
          float p = exp2f(fminf(vv, 86.0f));
          lsum[i][r] += p;
          Pw[i * 1152 + r * 72 + j * 16] = f2b(p);
        }

    // PV
#pragma unroll
    for (int kk = 0; kk < 2; ++kk) {
      bf16x8 pf[2], vf[4];
#pragma unroll
      for (int i = 0; i < 2; ++i)
        pf[i] = *(const bf16x8*)&Pr[i * 1152 + kk * 32];
#pragma unroll
      for (int j = 0; j < 4; ++j) {
        int r = j * 16 + lrow;
        vf[j] = *(const bf16x8*)&Vb[r * 64 + ((((kk << 2) | lk) ^ (r & 7)) << 3)];
      }
#pragma unroll
      for (int i = 0; i < 2; ++i)
#pragma unroll
        for (int j = 0; j < 4; ++j)
          o[i][j] = __builtin_amdgcn_mfma_f32_16x16x32_bf16(pf[i], vf[j], o[i][j], 0, 0, 0);
    }
    __syncthreads();  // staging drained + all readers of cur done
  }

  // deferred denominator: reduce over the 16-lane key dimension, once
#pragma unroll
  for (int i = 0; i < 2; ++i)
#pragma unroll
    for (int r = 0; r < 4; ++r) {
      float s = lsum[i][r];
      s += __shfl_xor(s, 1);
      s += __shfl_xor(s, 2);
      s += __shfl_xor(s, 4);
      s += __shfl_xor(s, 8);
      float inv = 1.0f / s;
#pragma unroll
      for (int j = 0; j < 4; ++j)
        localf[((long)b * 2048 + t0 + w * 32 + i * 16 + lk * 4 + r) * 1024
               + h * 64 + j * 16 + lrow] = f2b(o[i][j][r] * inv);
    }
}

// ---------------- launch ----------------
extern "C" void kernel_launch(void* const* d_in, const int* in_sizes, int n_in,
                              void* d_out, int out_size, void* d_ws, size_t ws_size,
                              hipStream_t stream) {
  (void)in_sizes; (void)n_in; (void)out_size; (void)ws_size;
  const float* x      = (const float*)d_in[0];
  const float* W_attn = (const float*)d_in[1];
  const float* b_attn = (const float*)d_in[2];
  const float* W_proj = (const float*)d_in[3];
  const float* b_proj = (const float*)d_in[4];
  const float* rel    = (const float*)d_in[5];
  const float* alpha  = (const float*)d_in[6];
  const float* W_lat  = (const float*)d_in[7];
  const float* b_lat  = (const float*)d_in[8];
  const float* W_fuse = (const float*)d_in[9];
  const float* b_fuse = (const float*)d_in[10];
  float* out = (float*)d_out;
  char* ws = (char*)d_ws;
  const size_t MiB = 1048576;

  u16*   xb       = (u16*)(ws + 0 * MiB);    // [4096][1024] bf16
  u16*   xT       = (u16*)(ws + 8 * MiB);    // [2][1024][2048] bf16
  u16*   WaT      = (u16*)(ws + 16 * MiB);   // [3072][1024] bf16
  u16*   Hb       = (u16*)(ws + 22 * MiB);   // [2048][2048] bf16
  u16*   xm       = (u16*)(ws + 30 * MiB);   // [2][2048][1024] bf16 (= H x)
  u16*   qkm2     = (u16*)(ws + 38 * MiB);   // [4096][2048] bf16 (q|k modulated)
  u16*   v        = (u16*)(ws + 54 * MiB);   // [4096][1024] bf16
  u16*   vT       = (u16*)(ws + 62 * MiB);   // [2][1024][2048] bf16
  u16*   localf   = (u16*)(ws + 70 * MiB);   // [4096][1024] bf16
  u16*   WcombT   = (u16*)(ws + 78 * MiB);   // [1024][1024] bf16
  float* hbuf     = (float*)(ws + 80 * MiB);
  float* out_const= (float*)(ws + 80 * MiB + 16384);
  int*   flags    = (int*)(ws + 80 * MiB + 32768);
  float* part     = (float*)(ws + 80 * MiB + 65536);  // [2][16][1024] f32

  // 1. prep (inputs only): cvt, transposes, Wcomb, conv_h, flag-zero
  prep_k<<<12032, 256, 0, stream>>>(x, W_attn, W_fuse, W_proj, alpha,
                                    xb, WaT, xT, WcombT, hbuf, flags);
  // 2. bias scan + Hb fill
  scanhb_k<<<17408, 256, 0, stream>>>(rel, flags, hbuf, Hb);

  GemmOffsets g0; for (int i = 0; i < 4; ++i) { g0.a[i]=0; g0.b[i]=0; g0.c[i]=0; }

  // 3. Gx: xm[b] = Hb @ x[b]   [2048,2048]@[2048,1024], z=b
  GemmOffsets gx;
  for (int i = 0; i < 4; ++i) { gx.a[i] = 0; gx.b[i] = (long)i * 1024 * 2048; gx.c[i] = (long)i * 2048 * 1024; }
  gemm_bt_k<0, false><<<dim3(8, 16, 2), 256, 0, stream>>>(
      Hb, 2048, xT, 2048, (void*)xm, 1024, 2048, nullptr, gx);

  // 4. G1a: v = x @ W_v + b_v   [4096,1024]@[1024,1024]
  gemm_bt_k<1, false><<<dim3(8, 32, 1), 256, 0, stream>>>(
      xb, 1024, WaT + (long)2048 * 1024, 1024, (void*)v, 1024, 1024, b_attn + 2048, g0);

  // 5. G1b: qkm2 = xm @ W_qk + b_qk   [4096,1024]@[1024,2048]
  gemm_bt_k<1, false><<<dim3(16, 32, 1), 256, 0, stream>>>(
      xm, 1024, WaT, 1024, (void*)qkm2, 2048, 1024, b_attn, g0);

  // 6. V transpose + v-mean partials
  tVvm_k<<<1056, 256, 0, stream>>>(v, vT, part);

  // 7. latent chain -> out_const
  latent_k<<<2, 1024, 0, stream>>>(part, W_lat, b_lat, W_fuse, b_fuse,
                                   W_proj, b_proj, out_const);

  // 8. flash attention -> localf
  fa_k<<<dim3(2, 16, 16), 256, 0, stream>>>(qkm2, vT, rel, flags, localf);

  // 9. G3: out = localf @ WcombT^T + out_const[b]
  gemm_bt_k<2, true><<<dim3(8, 32, 1), 256, 0, stream>>>(
      localf, 1024, WcombT, 1024, (void*)out, 1024, 1024, out_const, g0);
}

// Round 6
// 368.289 us; speedup vs baseline: 2.1963x; 1.1539x over previous
//
#include <hip/hip_runtime.h>

typedef unsigned short u16;
typedef __attribute__((ext_vector_type(8))) short bf16x8;
typedef __attribute__((ext_vector_type(4))) float f32x4;
typedef __attribute__((ext_vector_type(4))) unsigned short u16x4;

__device__ __forceinline__ u16 f2b(float f) {
  union { float f; unsigned u; } x; x.f = f;
  unsigned u = x.u;
  return (u16)((u + 0x7fffu + ((u >> 16) & 1u)) >> 16);
}
__device__ __forceinline__ float b2f(u16 b) {
  union { unsigned u; float f; } x; x.u = ((unsigned)b) << 16;
  return x.f;
}

// async global->LDS, 16B per lane; lds base must be wave-uniform.
__device__ __forceinline__ void gload_lds16(const void* g, void* l) {
  __builtin_amdgcn_global_load_lds(
      (const __attribute__((address_space(1))) void*)g,
      (__attribute__((address_space(3))) void*)l, 16, 0, 0);
}

// ---------------- fused prep: everything that depends only on raw inputs ----------------
// [0,4096): x->xb bf16; [4096,4864): W_attn->WaT; [4864,5888): x->xT;
// [5888,9984): WcombT; [9984,12032): conv_h; [12032,13056): rel_bias scan.
__device__ __forceinline__ void tr_f2b_body(const float* __restrict__ in,
                                            u16* __restrict__ out, int R, int C,
                                            int bx, int by, int t, float* tile) {
  int r0 = by * 64, c0 = bx * 64;
  for (int ch = t; ch < 1024; ch += 256) {
    int r = ch >> 4, q = ch & 15;
    float4 v = *(const float4*)(in + (long)(r0 + r) * C + c0 + q * 4);
    tile[r * 68 + q * 4 + 0] = v.x; tile[r * 68 + q * 4 + 1] = v.y;
    tile[r * 68 + q * 4 + 2] = v.z; tile[r * 68 + q * 4 + 3] = v.w;
  }
  __syncthreads();
  for (int ch = t; ch < 1024; ch += 256) {
    int cc = ch >> 4, g = ch & 15;
    u16x4 o;
    o[0] = f2b(tile[(g * 4 + 0) * 68 + cc]); o[1] = f2b(tile[(g * 4 + 1) * 68 + cc]);
    o[2] = f2b(tile[(g * 4 + 2) * 68 + cc]); o[3] = f2b(tile[(g * 4 + 3) * 68 + cc]);
    *(u16x4*)(out + (long)(c0 + cc) * R + r0 + g * 4) = o;
  }
}

__global__ void prep_k(const float* __restrict__ x, const float* __restrict__ W_attn,
                       const float* __restrict__ W_fuse, const float* __restrict__ W_proj,
                       const float* __restrict__ alpha, const float* __restrict__ rel,
                       u16* __restrict__ xb, u16* __restrict__ WaT, u16* __restrict__ xT,
                       u16* __restrict__ WcombT, float* __restrict__ hbuf,
                       int* __restrict__ flags) {
  __shared__ float smem[64 * 68];
  const int id = blockIdx.x, t = threadIdx.x;
  if (id == 0 && t < 16) flags[t] = 0;
  if (id < 4096) {                       // x -> xb bf16
    long i = ((long)id * 256 + t) * 4;
    float4 v = *(const float4*)(x + i);
    u16x4 o;
    o[0] = f2b(v.x); o[1] = f2b(v.y); o[2] = f2b(v.z); o[3] = f2b(v.w);
    *(u16x4*)(xb + i) = o;
  } else if (id < 4864) {                // W_attn[1024][3072] -> WaT[3072][1024]
    int local = id - 4096;
    tr_f2b_body(W_attn, WaT, 1024, 3072, local % 48, local / 48, t, smem);
  } else if (id < 5888) {                // x[z][2048][1024] -> xT[z][1024][2048]
    int local = id - 4864;
    int bx = local & 15, by = (local >> 4) & 31, z = local >> 9;
    tr_f2b_body(x + (long)z * 2048 * 1024, xT + (long)z * 1024 * 2048,
                2048, 1024, bx, by, t, smem);
  } else if (id < 9984) {                // WcombT[c][h*64+d0] = sum_d1 Wf[d0][d1] Wp[h*64+d1][c]
    long idx = (long)(id - 5888) * 256 + t;
    int c = (int)(idx >> 10), hd0 = (int)(idx & 1023);
    int h = hd0 >> 6, d0 = hd0 & 63;
    float acc = 0.f;
    for (int d1 = 0; d1 < 64; ++d1)
      acc += W_fuse[d0 * 64 + d1] * W_proj[(long)(h * 64 + d1) * 1024 + c];
    WcombT[(long)c * 1024 + hd0] = f2b(acc);
  } else if (id < 12032) {               // conv_h: h = irfft(exp(-j*alpha), n=2048)
    int tt = id - 9984;
    float a = alpha[0];
    const float wph = 3.14159265358979323846f / 1024.f;
    float acc = 0.f;
    for (int j = 1 + t; j < 1024; j += 256) {
      int ph = (j * tt) & 2047;
      acc += 2.f * __expf(-a * (float)j) * __cosf((float)ph * wph);
    }
    if (t == 0) {
      acc += 1.0f;
      int ph = (1024 * tt) & 2047;
      acc += __expf(-a * 1024.f) * __cosf((float)ph * wph);
    }
    float* red = smem;
    red[t] = acc;
    __syncthreads();
    for (int s = 128; s > 0; s >>= 1) {
      if (t < s) red[t] += red[t + s];
      __syncthreads();
    }
    if (t == 0) hbuf[tt] = red[0] * (1.f / 2048.f);
  } else {                               // per-head all-zero scan of rel_bias
    int local = id - 12032;
    long base = (long)local * 65536;
    int h = local >> 6;
    const float4* p = (const float4*)(rel + base);
    bool nz = false;
    for (int i = t; i < 16384; i += 256) {
      float4 v = p[i];
      nz = nz || (v.x != 0.f) || (v.y != 0.f) || (v.z != 0.f) || (v.w != 0.f);
    }
    if (nz) atomicOr(flags + h, 1);
  }
}

// Hb[tt][u] = h[(tt-u)&2047], vectorized 16 elems/thread
__global__ void hb2_k(const float* __restrict__ hbuf, u16* __restrict__ Hb) {
  long idx0 = ((long)blockIdx.x * 256 + threadIdx.x) * 16;
  int tt = (int)(idx0 >> 11), u0 = (int)(idx0 & 2047);
  u16x4 o;
#pragma unroll
  for (int g = 0; g < 4; ++g) {
#pragma unroll
    for (int e = 0; e < 4; ++e)
      o[e] = f2b(hbuf[(tt - (u0 + g * 4 + e)) & 2047]);
    *(u16x4*)(Hb + idx0 + g * 4) = o;
  }
}

// ---------------- shared bf16 MFMA GEMM body: C = A[M,K] @ Bt[N,K]^T ----------------
// m97 structure: 128x128 tile, BK=64, 4 waves, global_load_lds staging with
// linear LDS dest + inverse-swizzled global source; swizzled ds_read side.
// bias_mode: 0 none, 1 bias[col], 2 bias[(row>>11)*ldc+col], 3 bias[row]
__device__ __forceinline__ void gemm_body(
    const u16* __restrict__ Ab, int lda, const u16* __restrict__ Bb, int ldb,
    void* __restrict__ Cv, long coff, int ldc, int K, int m0, int n0,
    int bias_mode, const float* __restrict__ bias, bool out_f32,
    u16* As, u16* Bs) {
  const int t = threadIdx.x;
  const int w = t >> 6, l = t & 63;
  const int wr = (w >> 1) * 64, wc = (w & 1) * 64;
  const int lrow = l & 15, lk = l >> 4;

  f32x4 acc[4][4] = {};

  for (int k0 = 0; k0 < K; k0 += 64) {
    __syncthreads();
#pragma unroll
    for (int q = 0; q < 4; ++q) {
      int ch = (w * 4 + q) * 64 + l;       // linear 16B-chunk index
      int row = ch >> 3;
      int cg = (ch & 7) ^ (row & 7);       // inverse-swizzled source column
      gload_lds16(Ab + (long)(m0 + row) * lda + k0 + cg * 8, &As[(w * 4 + q) * 512]);
      gload_lds16(Bb + (long)(n0 + row) * ldb + k0 + cg * 8, &Bs[(w * 4 + q) * 512]);
    }
    __syncthreads();
#pragma unroll
    for (int kk = 0; kk < 2; ++kk) {
      bf16x8 af[4], bfr[4];
#pragma unroll
      for (int i = 0; i < 4; ++i) {
        int ar = wr + i * 16 + lrow;
        af[i] = *(const bf16x8*)&As[ar * 64 + ((((kk << 2) | lk) ^ (ar & 7)) << 3)];
        int br = wc + i * 16 + lrow;
        bfr[i] = *(const bf16x8*)&Bs[br * 64 + ((((kk << 2) | lk) ^ (br & 7)) << 3)];
      }
#pragma unroll
      for (int i = 0; i < 4; ++i)
#pragma unroll
        for (int j = 0; j < 4; ++j)
          acc[i][j] = __builtin_amdgcn_mfma_f32_16x16x32_bf16(af[i], bfr[j], acc[i][j], 0, 0, 0);
    }
  }

#pragma unroll
  for (int i = 0; i < 4; ++i)
#pragma unroll
    for (int j = 0; j < 4; ++j)
#pragma unroll
      for (int r = 0; r < 4; ++r) {
        int row = m0 + wr + i * 16 + lk * 4 + r;
        int col = n0 + wc + j * 16 + lrow;
        float v = acc[i][j][r];
        if (bias_mode == 1) v += bias[col];
        else if (bias_mode == 2) v += bias[(row >> 11) * ldc + col];
        else if (bias_mode == 3) v += bias[row];
        if (out_f32)
          ((float*)Cv)[coff + (long)row * ldc + col] = v;
        else
          ((u16*)Cv)[coff + (long)row * ldc + col] = f2b(v);
      }
}

// phase 1: fused Gx (xm = Hb @ x[b], 256 tiles) + vT (Wv @ xb[b]^T, 256 tiles)
__global__ __launch_bounds__(256)
void phase1_k(const u16* __restrict__ Hb, const u16* __restrict__ xT,
              const u16* __restrict__ xb, const u16* __restrict__ WaT,
              const float* __restrict__ b_attn,
              u16* __restrict__ xm, u16* __restrict__ vT) {
  __shared__ u16 As[128 * 64];
  __shared__ u16 Bs[128 * 64];
  const int id = blockIdx.x;
  if (id < 256) {   // Gx: xm[z][tt][c] = sum_u Hb[tt][u] x[z][u][c]
    int z = id >> 7, r = id & 127;           // 16 m-tiles x 8 n-tiles
    gemm_body(Hb, 2048, xT + (long)z * 1024 * 2048, 2048,
              (void*)xm, (long)z * 2048 * 1024, 1024, 2048,
              (r >> 3) * 128, (r & 7) * 128, 0, nullptr, false, As, Bs);
  } else {          // vT[z][c][t] = sum_k Wv[c][k] xb[z][t][k] + b_v[c]
    int id2 = id - 256;
    int z = id2 >> 7, r = id2 & 127;         // 8 m-tiles x 16 n-tiles
    gemm_body(WaT + (long)2048 * 1024, 1024, xb + (long)z * 2048 * 1024, 1024,
              (void*)vT, (long)z * 1024 * 2048, 2048, 1024,
              (r >> 4) * 128, (r & 15) * 128, 3, b_attn + 2048, false, As, Bs);
  }
}

// G1b: qkm2 = xm @ W_qk + b_qk  (grid (16,33); y==32 row does vT row-sums)
__global__ __launch_bounds__(256)
void g1b_k(const u16* __restrict__ xm, const u16* __restrict__ WaT,
           const float* __restrict__ b_attn, const u16* __restrict__ vT,
           u16* __restrict__ qkm2, float* __restrict__ part) {
  __shared__ u16 As[128 * 64];
  __shared__ u16 Bs[128 * 64];
  if (blockIdx.y == 32) {    // vmean partial: full row sums of vT (rows = b*1024+c)
    int row = blockIdx.x * 128 + (threadIdx.x >> 1);
    int half = threadIdx.x & 1;
    const bf16x8* src = (const bf16x8*)(vT + (long)row * 2048 + half * 1024);
    float s = 0.f;
    for (int i = 0; i < 128; ++i) {
      bf16x8 v = src[i];
#pragma unroll
      for (int k = 0; k < 8; ++k) s += b2f((u16)(unsigned short)v[k]);
    }
    s += __shfl_xor(s, 1);
    if (half == 0) part[row] = s;
    return;
  }
  gemm_body(xm, 1024, WaT, 1024, (void*)qkm2, 0L, 2048, 1024,
            blockIdx.y * 128, blockIdx.x * 128, 1, b_attn, false, As, Bs);
}

// G3: out = localf @ WcombT^T + out_const[b]
__global__ __launch_bounds__(256)
void g3_k(const u16* __restrict__ localf, const u16* __restrict__ WcombT,
          const float* __restrict__ out_const, float* __restrict__ out) {
  __shared__ u16 As[128 * 64];
  __shared__ u16 Bs[128 * 64];
  gemm_body(localf, 1024, WcombT, 1024, (void*)out, 0L, 1024, 1024,
            blockIdx.y * 128, blockIdx.x * 128, 2, out_const, true, As, Bs);
}

// ---------------- latent chain: mean->W_lat->W_fuse[64:]->W_proj const ----------------
__global__ void latent_k(const float* __restrict__ part, const float* __restrict__ W_lat,
                         const float* __restrict__ b_lat, const float* __restrict__ W_fuse,
                         const float* __restrict__ b_fuse, const float* __restrict__ W_proj,
                         const float* __restrict__ b_proj, float* __restrict__ out_const) {
  const int b = blockIdx.x, t = threadIdx.x;
  const int h = t >> 6, d = t & 63;
  __shared__ float mv[1024], lat[1024];
  mv[t] = part[(long)b * 1024 + t] * (1.f / 2048.f);
  __syncthreads();
  float acc = b_lat[d];
  for (int k = 0; k < 64; ++k) acc += mv[h * 64 + k] * W_lat[k * 64 + d];
  lat[t] = acc;
  __syncthreads();
  float acc2 = b_fuse[d];
  for (int k = 0; k < 64; ++k) acc2 += lat[h * 64 + k] * W_fuse[(64 + k) * 64 + d];
  __syncthreads();
  mv[t] = acc2;                           // lat_term
  __syncthreads();
  float acc3 = b_proj[t];
  for (int hd = 0; hd < 1024; ++hd) acc3 += mv[hd] * W_proj[(long)hd * 1024 + t];
  out_const[b * 1024 + t] = acc3;
}

// ---------------- flash attention ----------------
// grid (B, H, T/128); 256 thr, 4 waves; each wave owns 32 Q rows.
// qkm2 layout [b][t][{q:0..1023, k:1024..2047}], row stride 2048.
// vT layout [b][ch][t], row stride 2048.
__global__ __launch_bounds__(256)
void fa_k(const u16* __restrict__ qkm2, const u16* __restrict__ vT,
          const float* __restrict__ rel, const int* __restrict__ flags,
          u16* __restrict__ localf) {
  const int b = blockIdx.x, h = blockIdx.y;
  const int t0 = blockIdx.z * 128;
  const int t = threadIdx.x, w = t >> 6, l = t & 63;
  const int lrow = l & 15, lk = l >> 4;
  __shared__ u16 QPs[9216];      // Q staging (8192 u16), then per-wave P [32][72]
  __shared__ u16 Ks[2][64 * 64];
  __shared__ u16 Vs[2][64 * 64];

  const bool has_bias = (flags[h] != 0);
  const u16* qm = qkm2 + (long)b * 2048 * 2048;
  const u16* km = qm + 1024;

#pragma unroll
  for (int q = 0; q < 4; ++q) {
    int ch = (w * 4 + q) * 64 + l;
    int r = ch >> 3;
    int cg = (ch & 7) ^ (r & 7);
    gload_lds16(qm + (long)(t0 + r) * 2048 + h * 64 + cg * 8, &QPs[(w * 4 + q) * 512]);
  }
  auto stage = [&](int tile, int buf) {
    int s0 = tile * 64;
#pragma unroll
    for (int q = 0; q < 2; ++q) {
      int ch = (w * 2 + q) * 64 + l;
      int r = ch >> 3;
      int cg = (ch & 7) ^ (r & 7);
      gload_lds16(km + (long)(s0 + r) * 2048 + h * 64 + cg * 8,
                  &Ks[buf][(w * 2 + q) * 512]);
      gload_lds16(vT + ((long)b * 1024 + h * 64 + r) * 2048 + s0 + cg * 8,
                  &Vs[buf][(w * 2 + q) * 512]);
    }
  };
  stage(0, 0);
  __syncthreads();

  bf16x8 qf[2][2];
#pragma unroll
  for (int i = 0; i < 2; ++i)
#pragma unroll
    for (int kk = 0; kk < 2; ++kk) {
      int r = w * 32 + i * 16 + lrow;
      qf[i][kk] = *(const bf16x8*)&QPs[r * 64 + ((((kk << 2) | lk) ^ (r & 7)) << 3)];
    }
  __syncthreads();  // all waves done reading Q before any P store into QPs

  u16* Pw = QPs + w * 2304 + (lk * 4) * 72 + lrow;       // write base
  const u16* Pr = QPs + w * 2304 + lrow * 72 + lk * 8;   // read base

  f32x4 o[2][4] = {};
  float lsum[2][4] = {};

  for (int it = 0; it < 32; ++it) {
    const int cur = it & 1;
    const u16* Kb = Ks[cur];
    const u16* Vb = Vs[cur];

    f32x4 sa[2][4] = {};
#pragma unroll
    for (int kk = 0; kk < 2; ++kk) {
      bf16x8 kf[4];
#pragma unroll
      for (int j = 0; j < 4; ++j) {
        int r = j * 16 + lrow;
        kf[j] = *(const bf16x8*)&Kb[r * 64 + ((((kk << 2) | lk) ^ (r & 7)) << 3)];
      }
#pragma unroll
      for (int i = 0; i < 2; ++i)
#pragma unroll
        for (int j = 0; j < 4; ++j)
          sa[i][j] = __builtin_amdgcn_mfma_f32_16x16x32_bf16(qf[i][kk], kf[j], sa[i][j], 0, 0, 0);
    }

    if (it < 31) stage(it + 1, cur ^ 1);

#pragma unroll
    for (int i = 0; i < 2; ++i)
#pragma unroll
      for (int j = 0; j < 4; ++j)
#pragma unroll
        for (int r = 0; r < 4; ++r) {
          float vv = sa[i][j][r] * 0.1803368867f;  // 0.125 * log2(e)
          if (has_bias)
            vv += 1.4426950409f *
                  rel[((long)h * 2048 + t0 + w * 32 + i * 16 + lk * 4 + r) * 2048
                      + it * 64 + j * 16 + lrow];
          float p = exp2f(fminf(vv, 86.0f));
          lsum[i][r] += p;
          Pw[i * 1152 + r * 72 + j * 16] = f2b(p);
        }

#pragma unroll
    for (int kk = 0; kk < 2; ++kk) {
      bf16x8 pf[2], vf[4];
#pragma unroll
      for (int i = 0; i < 2; ++i)
        pf[i] = *(const bf16x8*)&Pr[i * 1152 + kk * 32];
#pragma unroll
      for (int j = 0; j < 4; ++j) {
        int r = j * 16 + lrow;
        vf[j] = *(const bf16x8*)&Vb[r * 64 + ((((kk << 2) | lk) ^ (r & 7)) << 3)];
      }
#pragma unroll
      for (int i = 0; i < 2; ++i)
#pragma unroll
        for (int j = 0; j < 4; ++j)
          o[i][j] = __builtin_amdgcn_mfma_f32_16x16x32_bf16(pf[i], vf[j], o[i][j], 0, 0, 0);
    }
    __syncthreads();
  }

#pragma unroll
  for (int i = 0; i < 2; ++i)
#pragma unroll
    for (int r = 0; r < 4; ++r) {
      float s = lsum[i][r];
      s += __shfl_xor(s, 1);
      s += __shfl_xor(s, 2);
      s += __shfl_xor(s, 4);
      s += __shfl_xor(s, 8);
      float inv = 1.0f / s;
#pragma unroll
      for (int j = 0; j < 4; ++j)
        localf[((long)b * 2048 + t0 + w * 32 + i * 16 + lk * 4 + r) * 1024
               + h * 64 + j * 16 + lrow] = f2b(o[i][j][r] * inv);
    }
}

// ---------------- launch ----------------
extern "C" void kernel_launch(void* const* d_in, const int* in_sizes, int n_in,
                              void* d_out, int out_size, void* d_ws, size_t ws_size,
                              hipStream_t stream) {
  (void)in_sizes; (void)n_in; (void)out_size; (void)ws_size;
  const float* x      = (const float*)d_in[0];
  const float* W_attn = (const float*)d_in[1];
  const float* b_attn = (const float*)d_in[2];
  const float* W_proj = (const float*)d_in[3];
  const float* b_proj = (const float*)d_in[4];
  const float* rel    = (const float*)d_in[5];
  const float* alpha  = (const float*)d_in[6];
  const float* W_lat  = (const float*)d_in[7];
  const float* b_lat  = (const float*)d_in[8];
  const float* W_fuse = (const float*)d_in[9];
  const float* b_fuse = (const float*)d_in[10];
  float* out = (float*)d_out;
  char* ws = (char*)d_ws;
  const size_t MiB = 1048576;

  u16*   xb       = (u16*)(ws + 0 * MiB);    // [4096][1024] bf16
  u16*   xT       = (u16*)(ws + 8 * MiB);    // [2][1024][2048] bf16
  u16*   WaT      = (u16*)(ws + 16 * MiB);   // [3072][1024] bf16
  u16*   Hb       = (u16*)(ws + 22 * MiB);   // [2048][2048] bf16
  u16*   xm       = (u16*)(ws + 30 * MiB);   // [2][2048][1024] bf16 (= H x)
  u16*   qkm2     = (u16*)(ws + 46 * MiB);   // [4096][2048] bf16 (q|k modulated)
  u16*   vT       = (u16*)(ws + 62 * MiB);   // [2][1024][2048] bf16
  u16*   localf   = (u16*)(ws + 70 * MiB);   // [4096][1024] bf16
  u16*   WcombT   = (u16*)(ws + 78 * MiB);   // [1024][1024] bf16
  float* hbuf     = (float*)(ws + 80 * MiB);
  float* out_const= (float*)(ws + 80 * MiB + 16384);
  int*   flags    = (int*)(ws + 80 * MiB + 32768);
  float* part     = (float*)(ws + 80 * MiB + 65536);  // [2048] f32 row sums

  // 1. prep: cvt, transposes, Wcomb, conv_h, flag-zero, rel_bias scan
  prep_k<<<13056, 256, 0, stream>>>(x, W_attn, W_fuse, W_proj, alpha, rel,
                                    xb, WaT, xT, WcombT, hbuf, flags);
  // 2. Hb fill
  hb2_k<<<1024, 256, 0, stream>>>(hbuf, Hb);

  // 3. phase1: Gx (xm) + vT, fused, 512 blocks
  phase1_k<<<512, 256, 0, stream>>>(Hb, xT, xb, WaT, b_attn, xm, vT);

  // 4. G1b: qkm2 = xm @ W_qk + b_qk; plus vT row-sum partials (y==32)
  g1b_k<<<dim3(16, 33), 256, 0, stream>>>(xm, WaT, b_attn, vT, qkm2, part);

  // 5. latent chain -> out_const
  latent_k<<<2, 1024, 0, stream>>>(part, W_lat, b_lat, W_fuse, b_fuse,
                                   W_proj, b_proj, out_const);

  // 6. flash attention -> localf
  fa_k<<<dim3(2, 16, 16), 256, 0, stream>>>(qkm2, vT, rel, flags, localf);

  // 7. G3: out = localf @ WcombT^T + out_const[b]
  g3_k<<<dim3(8, 32), 256, 0, stream>>>(localf, WcombT, out_const, out);
}